// Round 18
// baseline (16365.079 us; speedup 1.0000x reference)
//
#include <hip/hip_runtime.h>
#include <math.h>

#define NB 64
#define NH 512
#define NV 64
#define NT 200
#define NSTEP 199
#define GBLK 256
#define GTHR 512

#define RLX   __ATOMIC_RELAXED
#define AGENT __HIP_MEMORY_SCOPE_AGENT
#define WGRP  __HIP_MEMORY_SCOPE_WORKGROUP

typedef float f4v __attribute__((ext_vector_type(4)));

// ---------------- threefry / gumbel (verbatim R8) -------------------------
__device__ inline float gumbel_tf(unsigned f){
  const unsigned ksc[3] = {0u, 1u, 0x1BD11BDBu};
  unsigned x0 = 0u + ksc[0];
  unsigned x1 = f  + ksc[1];
  const int R0[4] = {13,15,26,6};
  const int R1[4] = {17,29,16,24};
  #pragma unroll
  for (int i = 0; i < 5; ++i){
    #pragma unroll
    for (int r = 0; r < 4; ++r){
      int rot = (i & 1) ? R1[r] : R0[r];
      x0 += x1;
      x1 = (x1 << rot) | (x1 >> (32 - rot));
      x1 ^= x0;
    }
    x0 += ksc[(i+1)%3];
    x1 += ksc[(i+2)%3] + (unsigned)(i+1);
  }
  unsigned bits = x0 ^ x1;
  float u = __uint_as_float((bits >> 9) | 0x3F800000u) - 1.0f;
  u = fmaxf(u, 1.17549435e-38f);
  return -logf(-logf(u));
}

__device__ inline float sigf(float x){ return 1.0f/(1.0f + expf(-x)); }

// ---------------- flag polls (verbatim R17) ----------------
__device__ inline void poll256(unsigned* flags, unsigned tgt){
  const int l = threadIdx.x & 63;
  #pragma unroll
  for (int j = 0; j < 4; ++j){
    while (__hip_atomic_load(&flags[(l*4 + j)*16], RLX, AGENT) < tgt){
      __builtin_amdgcn_s_sleep(1);
    }
  }
}
__device__ inline void poll64(unsigned* flags, unsigned tgt){
  const int l = threadIdx.x & 63;
  while (__hip_atomic_load(&flags[l*16], RLX, AGENT) < tgt){
    __builtin_amdgcn_s_sleep(1);
  }
}

// ---------------- block reductions (verbatim R8) ----------------
__device__ inline float blk_red_max(float v, float* scr){
  #pragma unroll
  for (int m = 1; m < 64; m <<= 1) v = fmaxf(v, __shfl_xor(v, m, 64));
  if ((threadIdx.x & 63) == 0) scr[threadIdx.x >> 6] = v;
  __syncthreads();
  float r = scr[0];
  #pragma unroll
  for (int i = 1; i < 8; ++i) r = fmaxf(r, scr[i]);
  __syncthreads();
  return r;
}
__device__ inline float blk_red_sum(float v, float* scr){
  #pragma unroll
  for (int m = 1; m < 64; m <<= 1) v += __shfl_xor(v, m, 64);
  if ((threadIdx.x & 63) == 0) scr[threadIdx.x >> 6] = v;
  __syncthreads();
  float r = 0.f;
  #pragma unroll
  for (int i = 0; i < 8; ++i) r += scr[i];
  __syncthreads();
  return r;
}

// ---------------- precompute kernels (verbatim R8 + ksT/vsT fill) -----------
__global__ void k_msum_part(const float* __restrict__ emb, const int* __restrict__ lens,
                            float* __restrict__ part){
  int blk = blockIdx.x, b = blk >> 3, lc = blk & 7;
  int len = lens[b];
  int l0 = lc*64, l1 = len < l0+64 ? len : l0+64;
  for (int h = threadIdx.x; h < 512; h += 256){
    float a = 0.f;
    for (int l = l0; l < l1; ++l) a += emb[(b*512 + l)*512 + h];
    part[blk*512 + h] = a;
  }
}
__global__ void k_msum(const float* __restrict__ part, float* __restrict__ msumT){
  int b = blockIdx.x;
  for (int h = threadIdx.x; h < 512; h += 256){
    float a = 0.f;
    #pragma unroll
    for (int lc = 0; lc < 8; ++lc) a += part[(b*8+lc)*512 + h];
    msumT[h*64 + b] = a;
  }
}
__global__ void k_kv(const float* __restrict__ msumT,
                     const float* __restrict__ kw, const float* __restrict__ kb,
                     const float* __restrict__ vw, const float* __restrict__ vb,
                     float* __restrict__ keysum, float* __restrict__ valsum){
  int which = blockIdx.x >> 7;
  int i = ((blockIdx.x & 127) << 2) + (threadIdx.x >> 6);
  int b = threadIdx.x & 63;
  const float* W = which ? vw : kw;
  float a = 0.f;
  for (int h = 0; h < 512; ++h) a = fmaf(msumT[h*64+b], W[i*512+h], a);
  float bias = which ? vb[i] : kb[i];
  float* out = which ? valsum : keysum;
  out[b*512 + i] = a + 512.0f*bias;
}
__global__ void k_ceT(const float* __restrict__ ce, float* __restrict__ ceT){
  int idx = blockIdx.x*256 + threadIdx.x;
  if (idx < 32768){ int v = idx >> 9, e = idx & 511; ceT[e*64 + v] = ce[v*512 + e]; }
}
__global__ void k_tok(const float* __restrict__ ceT, const float* __restrict__ w_ih,
                      const float* __restrict__ b_ih, const float* __restrict__ b_hh,
                      float* __restrict__ tok){
  int idx = blockIdx.x*256 + threadIdx.x;
  int v = idx & 63, row = idx >> 6;
  float a = 0.f;
  for (int e = 0; e < 512; ++e) a = fmaf(ceT[e*64+v], w_ih[row*1024 + e], a);
  tok[v*2048 + row] = a + b_ih[row] + b_hh[row];
}
__global__ void k_init(const float* __restrict__ keysum, const float* __restrict__ valsum,
                       const float* __restrict__ cdn_w,
                       float* __restrict__ cdnT, float* __restrict__ xT,
                       float* __restrict__ ksT, float* __restrict__ vsT,
                       float* __restrict__ out, unsigned* __restrict__ bar){
  int idx = blockIdx.x*256 + threadIdx.x;
  if (idx < 65536){
    int v = idx >> 10, k = idx & 1023;
    cdnT[k*64 + v] = cdn_w[idx];
  } else if (idx < 98304){
    int r = idx - 65536; int j = r >> 6, b = r & 63;
    xT[j*64 + b] = valsum[b*512 + j] * (1.0f/512.0f);
  } else if (idx < 131072){
    xT[idx - 65536] = 0.f;
  } else if (idx < 135168){
    int r = idx - 131072; int b = r >> 6, v = r & 63;
    out[b*12800 + v] = 0.f;
  } else if (idx < 135232){
    int b = idx - 135168;
    out[819200 + b*200] = 0.f;
  } else if (idx < 139328){
    bar[idx - 135232] = 0u;   // flags[256*16]
  } else if (idx < 172096){
    int r = idx - 139328; int j = r >> 6, b = r & 63;
    ksT[j*64 + b] = keysum[b*512 + j];       // raw transpose (bit-exact)
  } else if (idx < 204864){
    int r = idx - 172096; int j = r >> 6, b = r & 63;
    vsT[j*64 + b] = valsum[b*512 + j];
  }
}

// ---------------- main persistent loop kernel ----------------
// R17 skeleton. Change: B broadcasts softmax stats (m,S) instead of ctx;
// waves 0-3 (ctx rows) recompute cx elementwise from h (final at t1) with
// R8's EXACT op sequence: sc=(ks*h)/SCALE; e=expf(sc-m); cx=vs*(e/S).
// Identical input bits -> identical cx bits -> identical gates/logits.
// L-blocks recompute pb_c the same way. ctx broadcast + ctx writes removed.
__global__ __launch_bounds__(GTHR, 2) void k_loop(
    const float* __restrict__ w_ih, const float* __restrict__ w_hh,
    const int* __restrict__ batch_y, const float* __restrict__ tok,
    const float* __restrict__ keysum, const float* __restrict__ valsum,
    const float* __restrict__ cdnT, const float* __restrict__ cdn_b,
    const float* __restrict__ ksT, const float* __restrict__ vsT,
    float* __restrict__ mS, float* __restrict__ xT, float* __restrict__ hT3,
    float* __restrict__ out, unsigned* __restrict__ flags){
  __shared__ float W_lds[1024][8];
  __shared__ float red[8][8][64];
  __shared__ float gates_lds[8][64];
  __shared__ float cc_lds[2][64];
  __shared__ float pb_h[512], pb_c[512];
  __shared__ float pb_lp[8][64];
  __shared__ float scr[8];
  __shared__ int done_h, done_c, done_pb;

  const int tid = threadIdx.x;
  const int blk = blockIdx.x;
  const bool HASB = (blk < 64);
  const bool HASL = (blk >= 64 && blk < 128);

  if (tid == 0){ done_h = 0; done_c = 0; done_pb = 0; }
  for (int idx = tid; idx < 8192; idx += GTHR){
    int k = idx >> 3, r = idx & 7;
    int g = r >> 1, c = r & 1;
    int row = g*512 + blk*2 + c;
    W_lds[k][r] = (k < 512) ? w_ih[row*1024 + 512 + k] : w_hh[row*512 + (k - 512)];
  }
  if (tid < 128) cc_lds[tid >> 6][tid & 63] = 0.0f;
  __syncthreads();

  const int w = tid >> 6, l = tid & 63, kg = l >> 4, bg = l & 15;
  const float SCALE = 22.627416997969522f;

#define ISS1(R, JJ) do{ const float* _p = xin + (((kbase + (JJ)*4) << 6) | (bg << 2)); \
  asm volatile("global_load_dwordx4 %0, %1, off sc0 sc1" : "=v"(R) : "v"(_p)); }while(0)
#define ISS8(P, J0) do{ ISS1(P##0,(J0)+0);ISS1(P##1,(J0)+1);ISS1(P##2,(J0)+2);ISS1(P##3,(J0)+3); \
  ISS1(P##4,(J0)+4);ISS1(P##5,(J0)+5);ISS1(P##6,(J0)+6);ISS1(P##7,(J0)+7); }while(0)
#define CMPX(R, JJ) do{ int _k = kbase + (JJ)*4; \
  f4v _wA = *(const f4v*)&W_lds[_k][0]; f4v _wB = *(const f4v*)&W_lds[_k][4]; \
  float _wv[8] = {_wA.x,_wA.y,_wA.z,_wA.w,_wB.x,_wB.y,_wB.z,_wB.w}; \
  float _xv[4] = {R.x,R.y,R.z,R.w}; \
  _Pragma("unroll") for (int _r = 0; _r < 8; ++_r){ \
    _Pragma("unroll") for (int _q = 0; _q < 4; ++_q) \
      acc[_r][_q] = fmaf(_wv[_r], _xv[_q], acc[_r][_q]); } }while(0)
#define CMP8(P, J0) do{ CMPX(P##0,(J0)+0);CMPX(P##1,(J0)+1);CMPX(P##2,(J0)+2);CMPX(P##3,(J0)+3); \
  CMPX(P##4,(J0)+4);CMPX(P##5,(J0)+5);CMPX(P##6,(J0)+6);CMPX(P##7,(J0)+7); }while(0)
#define WAITV(N) do{ asm volatile("s_waitcnt vmcnt(" #N ")" ::: "memory"); \
  __builtin_amdgcn_sched_barrier(0); }while(0)

  for (int s = 0; s < NSTEP; ++s){
    const float* xin  = xT + (size_t)(s & 1)*65536;
    float*       xout = xT + (size_t)((s + 1) & 1)*65536;
    const unsigned t1 = (unsigned)(2*s + 1), t2 = (unsigned)(2*s + 2);
    const unsigned tgt_h = (s == 0) ? 0u : (unsigned)(2*s - 1);
    const unsigned tgt_c = (s == 0) ? 0u : (unsigned)(2*s);

    // ---- per-wave input gating (verbatim R17) ----
    if (w >= 4){
      if (w == 4){
        poll256(flags, tgt_h);
        __hip_atomic_store(&done_h, s + 1, RLX, WGRP);
      } else {
        while (__hip_atomic_load(&done_h, RLX, WGRP) < s + 1) __builtin_amdgcn_s_sleep(1);
      }
    } else {
      if (w == 0){
        poll64(flags, tgt_c);
        __hip_atomic_store(&done_c, s + 1, RLX, WGRP);
      } else {
        while (__hip_atomic_load(&done_c, RLX, WGRP) < s + 1) __builtin_amdgcn_s_sleep(1);
      }
    }

    // tok prefetch (verbatim R8)
    const int rr = tid >> 6, rb = tid & 63;
    int yprev = (s == 0) ? 0 : batch_y[rb*200 + s];
    float tokval = tok[yprev*2048 + (rr >> 1)*512 + blk*2 + (rr & 1)];

    // ---- Phase A ----
    float acc[8][4];
    #pragma unroll
    for (int r = 0; r < 8; ++r)
      #pragma unroll
      for (int q = 0; q < 4; ++q) acc[r][q] = 0.f;

    const int kbase = w*128 + kg;
    if (w >= 4 || s == 0){
      // verbatim R8 16-deep 1-stream (h rows for w>=4; ctx0 rows at s==0)
      f4v A0,A1,A2,A3,A4,A5,A6,A7,B0,B1,B2,B3,B4,B5,B6,B7;
      ISS8(A, 0);
      ISS8(B, 8);
      WAITV(8); CMP8(A, 0);
      ISS8(A, 16);
      WAITV(8); CMP8(B, 8);
      ISS8(B, 24);
      WAITV(8); CMP8(A, 16);
      WAITV(0); CMP8(B, 24);
    } else {
      // 3-stream 12-deep pipeline: h (coherent) + ksT/vsT (L2-hot normal);
      // recompute cx with R8-exact ops, then identical FMA sequence.
      f4v m4, S4;
      { const float* _mp = mS + (size_t)(s & 1)*128 + (bg << 2);
        asm volatile("global_load_dwordx4 %0, %1, off sc0 sc1" : "=v"(m4) : "v"(_mp));
        const float* _sp2 = _mp + 64;
        asm volatile("global_load_dwordx4 %0, %1, off sc0 sc1" : "=v"(S4) : "v"(_sp2)); }
      f4v xv[4], kv[4], vv[4];
      #pragma unroll
      for (int jj = 0; jj < 4; ++jj){
        int k = kbase + jj*4;
        const float* hp = xin + (((512 + k) << 6) | (bg << 2));
        const float* kp = ksT + ((k << 6) | (bg << 2));
        const float* vp = vsT + ((k << 6) | (bg << 2));
        asm volatile("global_load_dwordx4 %0, %1, off sc0 sc1" : "=v"(xv[jj]) : "v"(hp));
        asm volatile("global_load_dwordx4 %0, %1, off" : "=v"(kv[jj]) : "v"(kp));
        asm volatile("global_load_dwordx4 %0, %1, off" : "=v"(vv[jj]) : "v"(vp));
      }
      WAITV(12);   // m4,S4 landed
      #pragma unroll
      for (int jj = 0; jj < 32; ++jj){
        if (jj <= 28) WAITV(9); else if (jj == 29) WAITV(6); else if (jj == 30) WAITV(3); else WAITV(0);
        const int bank = jj & 3;
        f4v h4 = xv[bank], k4 = kv[bank], v4 = vv[bank];
        f4v cx4;
        { float sc0 = (k4.x*h4.x)/SCALE; float e0 = expf(sc0 - m4.x); cx4.x = v4.x*(e0/S4.x);
          float sc1 = (k4.y*h4.y)/SCALE; float e1 = expf(sc1 - m4.y); cx4.y = v4.y*(e1/S4.y);
          float sc2 = (k4.z*h4.z)/SCALE; float e2 = expf(sc2 - m4.z); cx4.z = v4.z*(e2/S4.z);
          float sc3 = (k4.w*h4.w)/SCALE; float e3 = expf(sc3 - m4.w); cx4.w = v4.w*(e3/S4.w); }
        CMPX(cx4, jj);
        if (jj < 28){
          int k = kbase + (jj + 4)*4;
          const float* hp = xin + (((512 + k) << 6) | (bg << 2));
          const float* kp = ksT + ((k << 6) | (bg << 2));
          const float* vp = vsT + ((k << 6) | (bg << 2));
          asm volatile("global_load_dwordx4 %0, %1, off sc0 sc1" : "=v"(xv[bank]) : "v"(hp));
          asm volatile("global_load_dwordx4 %0, %1, off" : "=v"(kv[bank]) : "v"(kp));
          asm volatile("global_load_dwordx4 %0, %1, off" : "=v"(vv[bank]) : "v"(vp));
        }
      }
    }

    // kg reduction + LDS partials (verbatim R8)
    #pragma unroll
    for (int r = 0; r < 8; ++r)
      #pragma unroll
      for (int q = 0; q < 4; ++q){
        float v = acc[r][q];
        v += __shfl_xor(v, 16, 64);
        v += __shfl_xor(v, 32, 64);
        acc[r][q] = v;
      }
    if (l < 16){
      #pragma unroll
      for (int r = 0; r < 8; ++r)
        *(float4*)&red[w][r][bg*4] = make_float4(acc[r][0], acc[r][1], acc[r][2], acc[r][3]);
    }
    __syncthreads();
    {
      float g = 0.f;
      #pragma unroll
      for (int ww = 0; ww < 8; ++ww) g += red[ww][rr][rb];
      gates_lds[rr][rb] = g + tokval;
    }
    __syncthreads();
    if (tid < 128){
      int c = tid >> 6, b = tid & 63;
      float ig = gates_lds[0 + c][b];
      float fg = gates_lds[2 + c][b];
      float gg = gates_lds[4 + c][b];
      float og = gates_lds[6 + c][b];
      float cprev = cc_lds[c][b];
      float cnew = sigf(fg)*cprev + sigf(ig)*tanhf(gg);
      float hnew = sigf(og)*tanhf(cnew);
      cc_lds[c][b] = cnew;
      float oldh = __hip_atomic_exchange(&xout[(512 + blk*2 + c)*64 + b], hnew, RLX, AGENT);
      asm volatile("" :: "v"(oldh));
      float oldt = __hip_atomic_exchange(
          &hT3[(size_t)((s + 1) % 3)*32768 + b*512 + (blk*2 + c)], hnew, RLX, AGENT);
      asm volatile("" :: "v"(oldt));
    }

    // ---- barrier-1 arrival ----
    asm volatile("s_waitcnt vmcnt(0)" ::: "memory");
    __syncthreads();
    if (tid == 0){
      unsigned o = __hip_atomic_exchange(&flags[blk*16], HASB ? t1 : t2, RLX, AGENT);
      asm volatile("" :: "v"(o));
    }

    if (HASB){
      if (w == 4){
        poll256(flags, t1);
        __hip_atomic_store(&done_pb, s + 1, RLX, WGRP);
      } else {
        while (__hip_atomic_load(&done_pb, RLX, WGRP) < s + 1) __builtin_amdgcn_s_sleep(1);
      }

      // ---- Phase B: softmax STATS only (FP verbatim R8 up to S) ----
      int b = blk;
      int jj = tid;
      float h;
      { const float* hp = hT3 + (size_t)((s + 1) % 3)*32768 + b*512 + jj;
        asm volatile("global_load_dword %0, %1, off sc0 sc1" : "=v"(h) : "v"(hp));
        asm volatile("s_waitcnt vmcnt(0)" ::: "memory"); }
      float sc = (keysum[b*512 + jj] * h) / SCALE;
      float m = blk_red_max(sc, scr);
      float e = expf(sc - m);
      float S = blk_red_sum(e, scr);
      float* mp = mS + (size_t)((s + 1) & 1)*128;
      if (tid == 0){
        float o = __hip_atomic_exchange(&mp[b], m, RLX, AGENT);
        asm volatile("" :: "v"(o));
      } else if (tid == 1){
        float o = __hip_atomic_exchange(&mp[64 + b], S, RLX, AGENT);
        asm volatile("" :: "v"(o));
      }
      asm volatile("s_waitcnt vmcnt(0)" ::: "memory");
      __syncthreads();
      if (tid == 0){
        unsigned o = __hip_atomic_exchange(&flags[blk*16], t2, RLX, AGENT);
        asm volatile("" :: "v"(o));
      }
    }

    if (HASL && s >= 1){
      // ---- pipelined logits + sampling for sp = s-1; pb_c recomputed
      //      from (h, m, S) with R8-exact ops ----
      int b = blk - 64;
      int sp = s - 1;
      float h, mm, SS;
      { const float* hp = hT3 + (size_t)(s % 3)*32768 + b*512 + tid;
        const float* mp = mS + (size_t)(s & 1)*128 + b;
        const float* sp2 = mp + 64;
        asm volatile("global_load_dword %0, %1, off sc0 sc1" : "=v"(h)  : "v"(hp));
        asm volatile("global_load_dword %0, %1, off sc0 sc1" : "=v"(mm) : "v"(mp));
        asm volatile("global_load_dword %0, %1, off sc0 sc1" : "=v"(SS) : "v"(sp2));
        asm volatile("s_waitcnt vmcnt(0)" ::: "memory"); }
      float sc = (keysum[b*512 + tid] * h) / SCALE;
      float e = expf(sc - mm);
      float c = valsum[b*512 + tid] * (e / SS);
      pb_h[tid] = h;
      pb_c[tid] = c;
      __syncthreads();
      int kq = tid >> 6, v = tid & 63;
      float part = 0.f;
      for (int k = kq*128; k < kq*128 + 128; ++k){
        float xh = (k < 512) ? pb_h[k] : pb_c[k - 512];
        part = fmaf(cdnT[k*64 + v], xh, part);
      }
      pb_lp[kq][v] = part;
      __syncthreads();
      if (tid < 64){
        int v2 = tid;
        float logit = cdn_b[v2];
        #pragma unroll
        for (int q = 0; q < 8; ++q) logit += pb_lp[q][v2];
        out[b*12800 + (sp+1)*64 + v2] = logit;
        float z = gumbel_tf((unsigned)((b*199 + sp)*64 + v2)) + logit;
        int idx = v2;
        #pragma unroll
        for (int mm2 = 1; mm2 < 64; mm2 <<= 1){
          float oz = __shfl_xor(z, mm2, 64);
          int   oi = __shfl_xor(idx, mm2, 64);
          if (oz > z || (oz == z && oi < idx)){ z = oz; idx = oi; }
        }
        if (v2 == 0) out[819200 + b*200 + (sp+1)] = (float)idx;
      }
    }
  }

  // ---- epilogue: logits/sampling for sp = 198 (L-blocks) ----
  if (HASL){
    int b = blk - 64;
    const int sp = NSTEP - 1;                      // 198
    if (tid == 0){
      while (__hip_atomic_load(&flags[b*16], RLX, AGENT) < (unsigned)(2*sp + 2))
        __builtin_amdgcn_s_sleep(1);
    }
    __syncthreads();
    float h, mm, SS;
    { const float* hp = hT3 + (size_t)((sp + 1) % 3)*32768 + b*512 + tid;
      const float* mp = mS + (size_t)((sp + 1) & 1)*128 + b;
      const float* sp2 = mp + 64;
      asm volatile("global_load_dword %0, %1, off sc0 sc1" : "=v"(h)  : "v"(hp));
      asm volatile("global_load_dword %0, %1, off sc0 sc1" : "=v"(mm) : "v"(mp));
      asm volatile("global_load_dword %0, %1, off sc0 sc1" : "=v"(SS) : "v"(sp2));
      asm volatile("s_waitcnt vmcnt(0)" ::: "memory"); }
    float sc = (keysum[b*512 + tid] * h) / SCALE;
    float e = expf(sc - mm);
    float c = valsum[b*512 + tid] * (e / SS);
    pb_h[tid] = h;
    pb_c[tid] = c;
    __syncthreads();
    int kq = tid >> 6, v = tid & 63;
    float part = 0.f;
    for (int k = kq*128; k < kq*128 + 128; ++k){
      float xh = (k < 512) ? pb_h[k] : pb_c[k - 512];
      part = fmaf(cdnT[k*64 + v], xh, part);
    }
    pb_lp[kq][v] = part;
    __syncthreads();
    if (tid < 64){
      int v2 = tid;
      float logit = cdn_b[v2];
      #pragma unroll
      for (int q = 0; q < 8; ++q) logit += pb_lp[q][v2];
      out[b*12800 + (sp+1)*64 + v2] = logit;
      float z = gumbel_tf((unsigned)((b*199 + sp)*64 + v2)) + logit;
      int idx = v2;
      #pragma unroll
      for (int mm2 = 1; mm2 < 64; mm2 <<= 1){
        float oz = __shfl_xor(z, mm2, 64);
        int   oi = __shfl_xor(idx, mm2, 64);
        if (oz > z || (oz == z && oi < idx)){ z = oz; idx = oi; }
      }
      if (v2 == 0) out[819200 + b*200 + (sp+1)] = (float)idx;
    }
  }
#undef ISS1
#undef ISS8
#undef CMPX
#undef CMP8
#undef WAITV
}

// ---------------- launcher ----------------
extern "C" void kernel_launch(void* const* d_in, const int* in_sizes, int n_in,
                              void* d_out, int out_size, void* d_ws, size_t ws_size,
                              hipStream_t stream){
  const float* seq     = (const float*)d_in[0];
  const float* key_w   = (const float*)d_in[1];
  const float* key_b   = (const float*)d_in[2];
  const float* value_w = (const float*)d_in[3];
  const float* value_b = (const float*)d_in[4];
  const float* char_e  = (const float*)d_in[5];
  const float* w_ih    = (const float*)d_in[6];
  const float* w_hh    = (const float*)d_in[7];
  const float* b_ih    = (const float*)d_in[8];
  const float* b_hh    = (const float*)d_in[9];
  const float* cdn_w   = (const float*)d_in[10];
  const float* cdn_b   = (const float*)d_in[11];
  const int*   lens    = (const int*)d_in[12];
  const int*   batch_y = (const int*)d_in[13];
  float* out = (float*)d_out;
  float* ws  = (float*)d_ws;

  // R8-proven 2.9 MB footprint. hT3/ksT/vsT/mS overlay the msum_part scratch
  // (dead after k_msum; ksT/vsT written by k_init which runs after k_msum).
  float* hT3       = ws;              // 3 x 32768  [b][row]
  float* ksT       = ws + 98304;      // 32768  [j][b] raw transpose
  float* vsT       = ws + 131072;     // 32768
  float* mS        = ws + 163840;     // 2 x 128  {m[64], S[64]}
  float* msum_part = ws;              // 262144 (precompute only)
  float* msumT     = ws + 262144;
  float* keysum    = ws + 294912;
  float* valsum    = ws + 327680;
  float* tok       = ws + 360448;
  float* cdnT      = ws + 491520;
  float* ceT       = ws + 557056;
  float* xT        = ws + 589824;     // 2 x 65536
  unsigned* bar    = (unsigned*)(ws + 720896); // flags[256*16]

  k_msum_part<<<512, 256, 0, stream>>>(seq, lens, msum_part);
  k_msum     <<<64,  256, 0, stream>>>(msum_part, msumT);
  k_kv       <<<256, 256, 0, stream>>>(msumT, key_w, key_b, value_w, value_b, keysum, valsum);
  k_ceT      <<<128, 256, 0, stream>>>(char_e, ceT);
  k_tok      <<<512, 256, 0, stream>>>(ceT, w_ih, b_ih, b_hh, tok);
  k_init     <<<801, 256, 0, stream>>>(keysum, valsum, cdn_w, cdnT, xT, ksT, vsT, out, bar);

  k_loop<<<GBLK, GTHR, 0, stream>>>(w_ih, w_hh, batch_y, tok, keysum, valsum,
                                    cdnT, cdn_b, ksT, vsT, mS, xT, hT3, out, bar);
  (void)in_sizes; (void)n_in; (void)out_size; (void)ws_size;
}

// Round 19
// 5384.626 us; speedup vs baseline: 3.0392x; 3.0392x over previous
//
#include <hip/hip_runtime.h>
#include <math.h>

#define NB 64
#define NH 512
#define NV 64
#define NT 200
#define NSTEP 199
#define GBLK 256
#define GTHR 512

#define RLX   __ATOMIC_RELAXED
#define AGENT __HIP_MEMORY_SCOPE_AGENT
#define WGRP  __HIP_MEMORY_SCOPE_WORKGROUP

typedef float f4v __attribute__((ext_vector_type(4)));

// ---------------- threefry / gumbel (verbatim R8) -------------------------
__device__ inline float gumbel_tf(unsigned f){
  const unsigned ksc[3] = {0u, 1u, 0x1BD11BDBu};
  unsigned x0 = 0u + ksc[0];
  unsigned x1 = f  + ksc[1];
  const int R0[4] = {13,15,26,6};
  const int R1[4] = {17,29,16,24};
  #pragma unroll
  for (int i = 0; i < 5; ++i){
    #pragma unroll
    for (int r = 0; r < 4; ++r){
      int rot = (i & 1) ? R1[r] : R0[r];
      x0 += x1;
      x1 = (x1 << rot) | (x1 >> (32 - rot));
      x1 ^= x0;
    }
    x0 += ksc[(i+1)%3];
    x1 += ksc[(i+2)%3] + (unsigned)(i+1);
  }
  unsigned bits = x0 ^ x1;
  float u = __uint_as_float((bits >> 9) | 0x3F800000u) - 1.0f;
  u = fmaxf(u, 1.17549435e-38f);
  return -logf(-logf(u));
}

__device__ inline float sigf(float x){ return 1.0f/(1.0f + expf(-x)); }

// ---------------- flag polls (verbatim R17) ----------------
__device__ inline void poll256(unsigned* flags, unsigned tgt){
  const int l = threadIdx.x & 63;
  #pragma unroll
  for (int j = 0; j < 4; ++j){
    while (__hip_atomic_load(&flags[(l*4 + j)*16], RLX, AGENT) < tgt){
      __builtin_amdgcn_s_sleep(1);
    }
  }
}
__device__ inline void poll64(unsigned* flags, unsigned tgt){
  const int l = threadIdx.x & 63;
  while (__hip_atomic_load(&flags[l*16], RLX, AGENT) < tgt){
    __builtin_amdgcn_s_sleep(1);
  }
}

// ---------------- block reductions (verbatim R8) ----------------
__device__ inline float blk_red_max(float v, float* scr){
  #pragma unroll
  for (int m = 1; m < 64; m <<= 1) v = fmaxf(v, __shfl_xor(v, m, 64));
  if ((threadIdx.x & 63) == 0) scr[threadIdx.x >> 6] = v;
  __syncthreads();
  float r = scr[0];
  #pragma unroll
  for (int i = 1; i < 8; ++i) r = fmaxf(r, scr[i]);
  __syncthreads();
  return r;
}
__device__ inline float blk_red_sum(float v, float* scr){
  #pragma unroll
  for (int m = 1; m < 64; m <<= 1) v += __shfl_xor(v, m, 64);
  if ((threadIdx.x & 63) == 0) scr[threadIdx.x >> 6] = v;
  __syncthreads();
  float r = 0.f;
  #pragma unroll
  for (int i = 0; i < 8; ++i) r += scr[i];
  __syncthreads();
  return r;
}

// ---------------- precompute kernels (verbatim R17) -----------
__global__ void k_msum_part(const float* __restrict__ emb, const int* __restrict__ lens,
                            float* __restrict__ part){
  int blk = blockIdx.x, b = blk >> 3, lc = blk & 7;
  int len = lens[b];
  int l0 = lc*64, l1 = len < l0+64 ? len : l0+64;
  for (int h = threadIdx.x; h < 512; h += 256){
    float a = 0.f;
    for (int l = l0; l < l1; ++l) a += emb[(b*512 + l)*512 + h];
    part[blk*512 + h] = a;
  }
}
__global__ void k_msum(const float* __restrict__ part, float* __restrict__ msumT){
  int b = blockIdx.x;
  for (int h = threadIdx.x; h < 512; h += 256){
    float a = 0.f;
    #pragma unroll
    for (int lc = 0; lc < 8; ++lc) a += part[(b*8+lc)*512 + h];
    msumT[h*64 + b] = a;
  }
}
__global__ void k_kv(const float* __restrict__ msumT,
                     const float* __restrict__ kw, const float* __restrict__ kb,
                     const float* __restrict__ vw, const float* __restrict__ vb,
                     float* __restrict__ keysum, float* __restrict__ valsum){
  int which = blockIdx.x >> 7;
  int i = ((blockIdx.x & 127) << 2) + (threadIdx.x >> 6);
  int b = threadIdx.x & 63;
  const float* W = which ? vw : kw;
  float a = 0.f;
  for (int h = 0; h < 512; ++h) a = fmaf(msumT[h*64+b], W[i*512+h], a);
  float bias = which ? vb[i] : kb[i];
  float* out = which ? valsum : keysum;
  out[b*512 + i] = a + 512.0f*bias;
}
__global__ void k_ceT(const float* __restrict__ ce, float* __restrict__ ceT){
  int idx = blockIdx.x*256 + threadIdx.x;
  if (idx < 32768){ int v = idx >> 9, e = idx & 511; ceT[e*64 + v] = ce[v*512 + e]; }
}
__global__ void k_tok(const float* __restrict__ ceT, const float* __restrict__ w_ih,
                      const float* __restrict__ b_ih, const float* __restrict__ b_hh,
                      float* __restrict__ tok){
  int idx = blockIdx.x*256 + threadIdx.x;
  int v = idx & 63, row = idx >> 6;
  float a = 0.f;
  for (int e = 0; e < 512; ++e) a = fmaf(ceT[e*64+v], w_ih[row*1024 + e], a);
  tok[v*2048 + row] = a + b_ih[row] + b_hh[row];
}
__global__ void k_init(const float* __restrict__ valsum, const float* __restrict__ cdn_w,
                       float* __restrict__ cdnT, float* __restrict__ xT,
                       float* __restrict__ out, unsigned* __restrict__ bar){
  int idx = blockIdx.x*256 + threadIdx.x;
  if (idx < 65536){
    int v = idx >> 10, k = idx & 1023;
    cdnT[k*64 + v] = cdn_w[idx];
  } else if (idx < 98304){
    int r = idx - 65536; int j = r >> 6, b = r & 63;
    xT[j*64 + b] = valsum[b*512 + j] * (1.0f/512.0f);
  } else if (idx < 131072){
    xT[idx - 65536] = 0.f;
  } else if (idx < 135168){
    int r = idx - 131072; int b = r >> 6, v = r & 63;
    out[b*12800 + v] = 0.f;
  } else if (idx < 135232){
    int b = idx - 135168;
    out[819200 + b*200] = 0.f;
  } else if (idx < 139328){
    bar[idx - 135232] = 0u;   // flags[256*16] incl. embedded xcnt/xdone/xread
  }
}

// ---------------- main persistent loop kernel ----------------
// R17 base (4824us, passing, bit-stable). Change: ctx half of the broadcast is
// served from a per-XCD L2 mirror (XCDs 0-6; XCD 7 keeps the R17 coherent
// path). Each local block copies a rank-strided share of ctx (coherent read,
// normal store -> local L2), bumps xdone[xcd]; readers wait xdone >= R*s and
// read via sc0 (L1-bypass, L2-hit). xread[xcd] (bumped after each block's
// Phase-A reads) keeps the single-buffered mirror overwrite-safe.
// All consumed values are exact copies -> FP bits identical to R17.
__global__ __launch_bounds__(GTHR, 2) void k_loop(
    const float* __restrict__ w_ih, const float* __restrict__ w_hh,
    const int* __restrict__ batch_y, const float* __restrict__ tok,
    const float* __restrict__ keysum, const float* __restrict__ valsum,
    const float* __restrict__ cdnT, const float* __restrict__ cdn_b,
    float* __restrict__ xT, float* __restrict__ hT3, float* __restrict__ wsb,
    float* __restrict__ out, unsigned* __restrict__ flags){
  __shared__ float W_lds[1024][8];
  __shared__ float red[8][8][64];
  __shared__ float gates_lds[8][64];
  __shared__ float cc_lds[2][64];
  __shared__ float pb_h[512], pb_c[512];
  __shared__ float pb_lp[8][64];
  __shared__ float scr[8];
  __shared__ int done_h, done_c, done_pb, done_m;
  __shared__ int cpy_done, myrank_s;

  const int tid = threadIdx.x;
  const int blk = blockIdx.x;
  const bool HASB = (blk < 64);
  const bool HASL = (blk >= 64 && blk < 128);

  unsigned xcc = 0;
  asm("s_getreg_b32 %0, hwreg(HW_REG_XCC_ID)" : "=s"(xcc));
  xcc &= 7u;
  const bool MIR = (xcc < 7u);
  // per-XCD counters embedded in unused words of the flag region
  unsigned* xcnt  = &flags[xcc*512 + 8];
  unsigned* xdone = &flags[xcc*512 + 136];
  unsigned* xread = &flags[xcc*512 + 264];
  // mirror chunk word-offsets (dead-after-precompute regions)
  const unsigned moff[7] = {98304u,131072u,163840u,196608u,229376u,262144u,557056u};
  float* mchunk = wsb + (MIR ? moff[xcc] : 0u);

  if (tid == 0){
    done_h = 0; done_c = 0; done_pb = 0; done_m = 0; cpy_done = 0;
    unsigned r = __hip_atomic_fetch_add(xcnt, 1u, RLX, AGENT);
    myrank_s = (int)r;
  }
  for (int idx = tid; idx < 8192; idx += GTHR){
    int k = idx >> 3, r = idx & 7;
    int g = r >> 1, c = r & 1;
    int row = g*512 + blk*2 + c;
    W_lds[k][r] = (k < 512) ? w_ih[row*1024 + 512 + k] : w_hh[row*512 + (k - 512)];
  }
  if (tid < 128) cc_lds[tid >> 6][tid & 63] = 0.0f;
  __syncthreads();
  const int myrank = myrank_s;

  const int w = tid >> 6, l = tid & 63, kg = l >> 4, bg = l & 15;
  const float SCALE = 22.627416997969522f;

#define ISSC(R, JJ) do{ const float* _p = xin + (((kbase + (JJ)*4) << 6) | (bg << 2)); \
  asm volatile("global_load_dwordx4 %0, %1, off sc0 sc1" : "=v"(R) : "v"(_p)); }while(0)
#define ISSM(R, JJ) do{ const float* _p = mchunk + (((kbase + (JJ)*4) << 6) | (bg << 2)); \
  asm volatile("global_load_dwordx4 %0, %1, off sc0" : "=v"(R) : "v"(_p)); }while(0)
#define ISSC8(P, J0) do{ ISSC(P##0,(J0)+0);ISSC(P##1,(J0)+1);ISSC(P##2,(J0)+2);ISSC(P##3,(J0)+3); \
  ISSC(P##4,(J0)+4);ISSC(P##5,(J0)+5);ISSC(P##6,(J0)+6);ISSC(P##7,(J0)+7); }while(0)
#define ISSM8(P, J0) do{ ISSM(P##0,(J0)+0);ISSM(P##1,(J0)+1);ISSM(P##2,(J0)+2);ISSM(P##3,(J0)+3); \
  ISSM(P##4,(J0)+4);ISSM(P##5,(J0)+5);ISSM(P##6,(J0)+6);ISSM(P##7,(J0)+7); }while(0)
#define CMPX(R, JJ) do{ int _k = kbase + (JJ)*4; \
  f4v _wA = *(const f4v*)&W_lds[_k][0]; f4v _wB = *(const f4v*)&W_lds[_k][4]; \
  float _wv[8] = {_wA.x,_wA.y,_wA.z,_wA.w,_wB.x,_wB.y,_wB.z,_wB.w}; \
  float _xv[4] = {R.x,R.y,R.z,R.w}; \
  _Pragma("unroll") for (int _r = 0; _r < 8; ++_r){ \
    _Pragma("unroll") for (int _q = 0; _q < 4; ++_q) \
      acc[_r][_q] = fmaf(_wv[_r], _xv[_q], acc[_r][_q]); } }while(0)
#define CMP8(P, J0) do{ CMPX(P##0,(J0)+0);CMPX(P##1,(J0)+1);CMPX(P##2,(J0)+2);CMPX(P##3,(J0)+3); \
  CMPX(P##4,(J0)+4);CMPX(P##5,(J0)+5);CMPX(P##6,(J0)+6);CMPX(P##7,(J0)+7); }while(0)
#define WAITV(N) do{ asm volatile("s_waitcnt vmcnt(" #N ")" ::: "memory"); \
  __builtin_amdgcn_sched_barrier(0); }while(0)

  for (int s = 0; s < NSTEP; ++s){
    const float* xin  = xT + (size_t)(s & 1)*65536;
    float*       xout = xT + (size_t)((s + 1) & 1)*65536;
    const unsigned t1 = (unsigned)(2*s + 1), t2 = (unsigned)(2*s + 2);
    const unsigned tgt_h = (s == 0) ? 0u : (unsigned)(2*s - 1);
    const unsigned tgt_c = (s == 0) ? 0u : (unsigned)(2*s);

    // ---- per-wave input gating ----
    if (w >= 4){
      if (w == 4){
        poll256(flags, tgt_h);
        __hip_atomic_store(&done_h, s + 1, RLX, WGRP);
      } else {
        while (__hip_atomic_load(&done_h, RLX, WGRP) < s + 1) __builtin_amdgcn_s_sleep(1);
      }
    } else {
      // waves 0-3 (ctx rows)
      if (w == 0){
        poll64(flags, tgt_c);
        if (MIR && s > 0){
          // mirror free to overwrite: all local blocks read it at step s-1
          unsigned need = (unsigned)(s - 1) * __hip_atomic_load(xcnt, RLX, AGENT);
          while (__hip_atomic_load(xread, RLX, AGENT) < need) __builtin_amdgcn_s_sleep(1);
        }
        __hip_atomic_store(&done_c, s + 1, RLX, WGRP);
      } else {
        while (__hip_atomic_load(&done_c, RLX, WGRP) < s + 1) __builtin_amdgcn_s_sleep(1);
      }
      if (MIR && s > 0){
        // distributed copy of ctx(s) into this XCD's mirror chunk
        unsigned Rv = __hip_atomic_load(xcnt, RLX, AGENT);
        unsigned t256 = (unsigned)((w << 6) | l);
        for (unsigned idx = (unsigned)myrank*256u + t256; idx < 8192u; idx += Rv*256u){
          f4v tmp;
          const float* sp = xin + (size_t)idx*4u;
          asm volatile("global_load_dwordx4 %0, %1, off sc0 sc1" : "=v"(tmp) : "v"(sp));
          asm volatile("s_waitcnt vmcnt(0)" ::: "memory");
          *(f4v*)(mchunk + (size_t)idx*4u) = tmp;
        }
        asm volatile("s_waitcnt vmcnt(0)" ::: "memory");
        if (l == 0){
          int o = __hip_atomic_fetch_add(&cpy_done, 1, RLX, WGRP);
          asm volatile("" :: "v"(o));
        }
        if (w == 0){
          if (l == 0){
            while (__hip_atomic_load(&cpy_done, RLX, WGRP) < 4*s) __builtin_amdgcn_s_sleep(1);
            unsigned o = __hip_atomic_fetch_add(xdone, 1u, RLX, AGENT);
            asm volatile("" :: "v"(o));
            unsigned need = (unsigned)s * Rv;
            while (__hip_atomic_load(xdone, RLX, AGENT) < need) __builtin_amdgcn_s_sleep(1);
          }
          __hip_atomic_store(&done_m, s + 1, RLX, WGRP);
        } else {
          while (__hip_atomic_load(&done_m, RLX, WGRP) < s + 1) __builtin_amdgcn_s_sleep(1);
        }
      }
    }

    // tok prefetch (verbatim R8)
    const int rr = tid >> 6, rb = tid & 63;
    int yprev = (s == 0) ? 0 : batch_y[rb*200 + s];
    float tokval = tok[yprev*2048 + (rr >> 1)*512 + blk*2 + (rr & 1)];

    // ---- Phase A (R17 pipeline; mirror variant differs only in load flags/base) ----
    float acc[8][4];
    #pragma unroll
    for (int r = 0; r < 8; ++r)
      #pragma unroll
      for (int q = 0; q < 4; ++q) acc[r][q] = 0.f;

    const int kbase = w*128 + kg;
    if (w < 4 && s > 0 && MIR){
      f4v A0,A1,A2,A3,A4,A5,A6,A7,B0,B1,B2,B3,B4,B5,B6,B7;
      ISSM8(A, 0);
      ISSM8(B, 8);
      WAITV(8); CMP8(A, 0);
      ISSM8(A, 16);
      WAITV(8); CMP8(B, 8);
      ISSM8(B, 24);
      WAITV(8); CMP8(A, 16);
      WAITV(0); CMP8(B, 24);
    } else {
      f4v A0,A1,A2,A3,A4,A5,A6,A7,B0,B1,B2,B3,B4,B5,B6,B7;
      ISSC8(A, 0);
      ISSC8(B, 8);
      WAITV(8); CMP8(A, 0);
      ISSC8(A, 16);
      WAITV(8); CMP8(B, 8);
      ISSC8(B, 24);
      WAITV(8); CMP8(A, 16);
      WAITV(0); CMP8(B, 24);
    }

    #pragma unroll
    for (int r = 0; r < 8; ++r)
      #pragma unroll
      for (int q = 0; q < 4; ++q){
        float v = acc[r][q];
        v += __shfl_xor(v, 16, 64);
        v += __shfl_xor(v, 32, 64);
        acc[r][q] = v;
      }
    if (l < 16){
      #pragma unroll
      for (int r = 0; r < 8; ++r)
        *(float4*)&red[w][r][bg*4] = make_float4(acc[r][0], acc[r][1], acc[r][2], acc[r][3]);
    }
    __syncthreads();
    if (tid == 0 && MIR && s > 0){
      unsigned o = __hip_atomic_fetch_add(xread, 1u, RLX, AGENT);
      asm volatile("" :: "v"(o));
    }
    {
      float g = 0.f;
      #pragma unroll
      for (int ww = 0; ww < 8; ++ww) g += red[ww][rr][rb];
      gates_lds[rr][rb] = g + tokval;
    }
    __syncthreads();
    if (tid < 128){
      int c = tid >> 6, b = tid & 63;
      float ig = gates_lds[0 + c][b];
      float fg = gates_lds[2 + c][b];
      float gg = gates_lds[4 + c][b];
      float og = gates_lds[6 + c][b];
      float cprev = cc_lds[c][b];
      float cnew = sigf(fg)*cprev + sigf(ig)*tanhf(gg);
      float hnew = sigf(og)*tanhf(cnew);
      cc_lds[c][b] = cnew;
      float oldh = __hip_atomic_exchange(&xout[(512 + blk*2 + c)*64 + b], hnew, RLX, AGENT);
      asm volatile("" :: "v"(oldh));
      float oldt = __hip_atomic_exchange(
          &hT3[(size_t)((s + 1) % 3)*32768 + b*512 + (blk*2 + c)], hnew, RLX, AGENT);
      asm volatile("" :: "v"(oldt));
    }

    // ---- barrier-1 arrival ----
    asm volatile("s_waitcnt vmcnt(0)" ::: "memory");
    __syncthreads();
    if (tid == 0){
      unsigned o = __hip_atomic_exchange(&flags[blk*16], HASB ? t1 : t2, RLX, AGENT);
      asm volatile("" :: "v"(o));
    }

    if (HASB){
      if (w == 4){
        poll256(flags, t1);
        __hip_atomic_store(&done_pb, s + 1, RLX, WGRP);
      } else {
        while (__hip_atomic_load(&done_pb, RLX, WGRP) < s + 1) __builtin_amdgcn_s_sleep(1);
      }

      // ---- Phase B core (softmax + ctx to xout only; FP verbatim R8) ----
      int b = blk;
      int jj = tid;
      float h;
      { const float* hp = hT3 + (size_t)((s + 1) % 3)*32768 + b*512 + jj;
        asm volatile("global_load_dword %0, %1, off sc0 sc1" : "=v"(h) : "v"(hp));
        asm volatile("s_waitcnt vmcnt(0)" ::: "memory"); }
      pb_h[jj] = h;
      float sc = (keysum[b*512 + jj] * h) / SCALE;
      float m = blk_red_max(sc, scr);
      float e = expf(sc - m);
      float S = blk_red_sum(e, scr);
      float cx = valsum[b*512 + jj] * (e / S);
      float oldc = __hip_atomic_exchange(&xout[jj*64 + b], cx, RLX, AGENT);
      asm volatile("" :: "v"(oldc));
      asm volatile("s_waitcnt vmcnt(0)" ::: "memory");
      __syncthreads();
      if (tid == 0){
        unsigned o = __hip_atomic_exchange(&flags[blk*16], t2, RLX, AGENT);
        asm volatile("" :: "v"(o));
      }
    }

    if (HASL && s >= 1){
      // ---- pipelined logits + sampling for sp = s-1 (off critical path) ----
      // ctx(s) read from xT slot s&1 (stable until B's Phase-B(s+1), which
      // transitively waits for this block's barrier-1(s+1)).
      int b = blk - 64;
      int sp = s - 1;
      float h, c;
      { const float* hp = hT3 + (size_t)(s % 3)*32768 + b*512 + tid;
        const float* cp = xT + (size_t)(s & 1)*65536 + tid*64 + b;
        asm volatile("global_load_dword %0, %1, off sc0 sc1" : "=v"(h) : "v"(hp));
        asm volatile("global_load_dword %0, %1, off sc0 sc1" : "=v"(c) : "v"(cp));
        asm volatile("s_waitcnt vmcnt(0)" ::: "memory"); }
      pb_h[tid] = h;
      pb_c[tid] = c;
      __syncthreads();
      int kq = tid >> 6, v = tid & 63;
      float part = 0.f;
      for (int k = kq*128; k < kq*128 + 128; ++k){
        float xh = (k < 512) ? pb_h[k] : pb_c[k - 512];
        part = fmaf(cdnT[k*64 + v], xh, part);
      }
      pb_lp[kq][v] = part;
      __syncthreads();
      if (tid < 64){
        int v2 = tid;
        float logit = cdn_b[v2];
        #pragma unroll
        for (int q = 0; q < 8; ++q) logit += pb_lp[q][v2];
        out[b*12800 + (sp+1)*64 + v2] = logit;
        float z = gumbel_tf((unsigned)((b*199 + sp)*64 + v2)) + logit;
        int idx = v2;
        #pragma unroll
        for (int mm = 1; mm < 64; mm <<= 1){
          float oz = __shfl_xor(z, mm, 64);
          int   oi = __shfl_xor(idx, mm, 64);
          if (oz > z || (oz == z && oi < idx)){ z = oz; idx = oi; }
        }
        if (v2 == 0) out[819200 + b*200 + (sp+1)] = (float)idx;
      }
    }
  }

  // ---- epilogue: logits/sampling for sp = 198 (L-blocks) ----
  if (HASL){
    int b = blk - 64;
    const int sp = NSTEP - 1;                      // 198
    if (tid == 0){
      while (__hip_atomic_load(&flags[b*16], RLX, AGENT) < (unsigned)(2*sp + 2))
        __builtin_amdgcn_s_sleep(1);
    }
    __syncthreads();
    float h, c;
    { const float* hp = hT3 + (size_t)((sp + 1) % 3)*32768 + b*512 + tid;
      const float* cp = xT + (size_t)((sp + 1) & 1)*65536 + tid*64 + b;
      asm volatile("global_load_dword %0, %1, off sc0 sc1" : "=v"(h) : "v"(hp));
      asm volatile("global_load_dword %0, %1, off sc0 sc1" : "=v"(c) : "v"(cp));
      asm volatile("s_waitcnt vmcnt(0)" ::: "memory"); }
    pb_h[tid] = h;
    pb_c[tid] = c;
    __syncthreads();
    int kq = tid >> 6, v = tid & 63;
    float part = 0.f;
    for (int k = kq*128; k < kq*128 + 128; ++k){
      float xh = (k < 512) ? pb_h[k] : pb_c[k - 512];
      part = fmaf(cdnT[k*64 + v], xh, part);
    }
    pb_lp[kq][v] = part;
    __syncthreads();
    if (tid < 64){
      int v2 = tid;
      float logit = cdn_b[v2];
      #pragma unroll
      for (int q = 0; q < 8; ++q) logit += pb_lp[q][v2];
      out[b*12800 + (sp+1)*64 + v2] = logit;
      float z = gumbel_tf((unsigned)((b*199 + sp)*64 + v2)) + logit;
      int idx = v2;
      #pragma unroll
      for (int mm = 1; mm < 64; mm <<= 1){
        float oz = __shfl_xor(z, mm, 64);
        int   oi = __shfl_xor(idx, mm, 64);
        if (oz > z || (oz == z && oi < idx)){ z = oz; idx = oi; }
      }
      if (v2 == 0) out[819200 + b*200 + (sp+1)] = (float)idx;
    }
  }
#undef ISSC
#undef ISSM
#undef ISSC8
#undef ISSM8
#undef CMPX
#undef CMP8
#undef WAITV
}

// ---------------- launcher ----------------
extern "C" void kernel_launch(void* const* d_in, const int* in_sizes, int n_in,
                              void* d_out, int out_size, void* d_ws, size_t ws_size,
                              hipStream_t stream){
  const float* seq     = (const float*)d_in[0];
  const float* key_w   = (const float*)d_in[1];
  const float* key_b   = (const float*)d_in[2];
  const float* value_w = (const float*)d_in[3];
  const float* value_b = (const float*)d_in[4];
  const float* char_e  = (const float*)d_in[5];
  const float* w_ih    = (const float*)d_in[6];
  const float* w_hh    = (const float*)d_in[7];
  const float* b_ih    = (const float*)d_in[8];
  const float* b_hh    = (const float*)d_in[9];
  const float* cdn_w   = (const float*)d_in[10];
  const float* cdn_b   = (const float*)d_in[11];
  const int*   lens    = (const int*)d_in[12];
  const int*   batch_y = (const int*)d_in[13];
  float* out = (float*)d_out;
  float* ws  = (float*)d_ws;

  // R8-proven 2.9 MB footprint. Mirror chunks + hT3 overlay dead-after-
  // precompute regions: hT3 [0,98304); ctx mirrors at [98304,294912) (6 chunks,
  // incl. msumT's slot) and ceT [557056,589824) (7th chunk).
  float* hT3       = ws;              // 3 x 32768  [b][row]
  float* msum_part = ws;              // 262144 (precompute only)
  float* msumT     = ws + 262144;     // 32768 (precompute only; mirror chunk 5)
  float* keysum    = ws + 294912;
  float* valsum    = ws + 327680;
  float* tok       = ws + 360448;
  float* cdnT      = ws + 491520;
  float* ceT       = ws + 557056;     // precompute only; mirror chunk 6
  float* xT        = ws + 589824;     // 2 x 65536
  unsigned* bar    = (unsigned*)(ws + 720896); // flags[256*16] + embedded counters

  k_msum_part<<<512, 256, 0, stream>>>(seq, lens, msum_part);
  k_msum     <<<64,  256, 0, stream>>>(msum_part, msumT);
  k_kv       <<<256, 256, 0, stream>>>(msumT, key_w, key_b, value_w, value_b, keysum, valsum);
  k_ceT      <<<128, 256, 0, stream>>>(char_e, ceT);
  k_tok      <<<512, 256, 0, stream>>>(ceT, w_ih, b_ih, b_hh, tok);
  k_init     <<<545, 256, 0, stream>>>(valsum, cdn_w, cdnT, xT, out, bar);

  k_loop<<<GBLK, GTHR, 0, stream>>>(w_ih, w_hh, batch_y, tok, keysum, valsum,
                                    cdnT, cdn_b, xT, hT3, ws, out, bar);
  (void)in_sizes; (void)n_in; (void)out_size; (void)ws_size;
}

// Round 20
// 4929.445 us; speedup vs baseline: 3.3199x; 1.0923x over previous
//
#include <hip/hip_runtime.h>
#include <math.h>

#define NB 64
#define NH 512
#define NV 64
#define NT 200
#define NSTEP 199
#define GBLK 256
#define GTHR 512

#define RLX   __ATOMIC_RELAXED
#define AGENT __HIP_MEMORY_SCOPE_AGENT
#define WGRP  __HIP_MEMORY_SCOPE_WORKGROUP

typedef float f4v __attribute__((ext_vector_type(4)));

// ---------------- threefry / gumbel (verbatim R8) -------------------------
__device__ inline float gumbel_tf(unsigned f){
  const unsigned ksc[3] = {0u, 1u, 0x1BD11BDBu};
  unsigned x0 = 0u + ksc[0];
  unsigned x1 = f  + ksc[1];
  const int R0[4] = {13,15,26,6};
  const int R1[4] = {17,29,16,24};
  #pragma unroll
  for (int i = 0; i < 5; ++i){
    #pragma unroll
    for (int r = 0; r < 4; ++r){
      int rot = (i & 1) ? R1[r] : R0[r];
      x0 += x1;
      x1 = (x1 << rot) | (x1 >> (32 - rot));
      x1 ^= x0;
    }
    x0 += ksc[(i+1)%3];
    x1 += ksc[(i+2)%3] + (unsigned)(i+1);
  }
  unsigned bits = x0 ^ x1;
  float u = __uint_as_float((bits >> 9) | 0x3F800000u) - 1.0f;
  u = fmaxf(u, 1.17549435e-38f);
  return -logf(-logf(u));
}

__device__ inline float sigf(float x){ return 1.0f/(1.0f + expf(-x)); }

// ---------------- flag polls ----------------
// all 256 flags (one wave: 64 lanes x 4) — used by wave 4 h-gate relay
__device__ inline void poll256(unsigned* flags, unsigned tgt){
  const int l = threadIdx.x & 63;
  #pragma unroll
  for (int j = 0; j < 4; ++j){
    while (__hip_atomic_load(&flags[(l*4 + j)*16], RLX, AGENT) < tgt){
      __builtin_amdgcn_s_sleep(1);
    }
  }
}
// B-block flags only (0..63), one lane each; wave reconvergence = all passed
__device__ inline void poll64(unsigned* flags, unsigned tgt){
  const int l = threadIdx.x & 63;
  while (__hip_atomic_load(&flags[l*16], RLX, AGENT) < tgt){
    __builtin_amdgcn_s_sleep(1);
  }
}

// ---------------- block reductions (verbatim R8) ----------------
__device__ inline float blk_red_max(float v, float* scr){
  #pragma unroll
  for (int m = 1; m < 64; m <<= 1) v = fmaxf(v, __shfl_xor(v, m, 64));
  if ((threadIdx.x & 63) == 0) scr[threadIdx.x >> 6] = v;
  __syncthreads();
  float r = scr[0];
  #pragma unroll
  for (int i = 1; i < 8; ++i) r = fmaxf(r, scr[i]);
  __syncthreads();
  return r;
}
__device__ inline float blk_red_sum(float v, float* scr){
  #pragma unroll
  for (int m = 1; m < 64; m <<= 1) v += __shfl_xor(v, m, 64);
  if ((threadIdx.x & 63) == 0) scr[threadIdx.x >> 6] = v;
  __syncthreads();
  float r = 0.f;
  #pragma unroll
  for (int i = 0; i < 8; ++i) r += scr[i];
  __syncthreads();
  return r;
}

// ---------------- precompute kernels (verbatim R17) -----------
__global__ void k_msum_part(const float* __restrict__ emb, const int* __restrict__ lens,
                            float* __restrict__ part){
  int blk = blockIdx.x, b = blk >> 3, lc = blk & 7;
  int len = lens[b];
  int l0 = lc*64, l1 = len < l0+64 ? len : l0+64;
  for (int h = threadIdx.x; h < 512; h += 256){
    float a = 0.f;
    for (int l = l0; l < l1; ++l) a += emb[(b*512 + l)*512 + h];
    part[blk*512 + h] = a;
  }
}
__global__ void k_msum(const float* __restrict__ part, float* __restrict__ msumT){
  int b = blockIdx.x;
  for (int h = threadIdx.x; h < 512; h += 256){
    float a = 0.f;
    #pragma unroll
    for (int lc = 0; lc < 8; ++lc) a += part[(b*8+lc)*512 + h];
    msumT[h*64 + b] = a;
  }
}
__global__ void k_kv(const float* __restrict__ msumT,
                     const float* __restrict__ kw, const float* __restrict__ kb,
                     const float* __restrict__ vw, const float* __restrict__ vb,
                     float* __restrict__ keysum, float* __restrict__ valsum){
  int which = blockIdx.x >> 7;
  int i = ((blockIdx.x & 127) << 2) + (threadIdx.x >> 6);
  int b = threadIdx.x & 63;
  const float* W = which ? vw : kw;
  float a = 0.f;
  for (int h = 0; h < 512; ++h) a = fmaf(msumT[h*64+b], W[i*512+h], a);
  float bias = which ? vb[i] : kb[i];
  float* out = which ? valsum : keysum;
  out[b*512 + i] = a + 512.0f*bias;
}
__global__ void k_ceT(const float* __restrict__ ce, float* __restrict__ ceT){
  int idx = blockIdx.x*256 + threadIdx.x;
  if (idx < 32768){ int v = idx >> 9, e = idx & 511; ceT[e*64 + v] = ce[v*512 + e]; }
}
__global__ void k_tok(const float* __restrict__ ceT, const float* __restrict__ w_ih,
                      const float* __restrict__ b_ih, const float* __restrict__ b_hh,
                      float* __restrict__ tok){
  int idx = blockIdx.x*256 + threadIdx.x;
  int v = idx & 63, row = idx >> 6;
  float a = 0.f;
  for (int e = 0; e < 512; ++e) a = fmaf(ceT[e*64+v], w_ih[row*1024 + e], a);
  tok[v*2048 + row] = a + b_ih[row] + b_hh[row];
}
__global__ void k_init(const float* __restrict__ valsum, const float* __restrict__ cdn_w,
                       float* __restrict__ cdnT, float* __restrict__ xT,
                       float* __restrict__ out, unsigned* __restrict__ bar){
  int idx = blockIdx.x*256 + threadIdx.x;
  if (idx < 65536){
    int v = idx >> 10, k = idx & 1023;
    cdnT[k*64 + v] = cdn_w[idx];
  } else if (idx < 98304){
    int r = idx - 65536; int j = r >> 6, b = r & 63;
    xT[j*64 + b] = valsum[b*512 + j] * (1.0f/512.0f);
  } else if (idx < 131072){
    xT[idx - 65536] = 0.f;
  } else if (idx < 135168){
    int r = idx - 131072; int b = r >> 6, v = r & 63;
    out[b*12800 + v] = 0.f;
  } else if (idx < 135232){
    int b = idx - 135168;
    out[819200 + b*200] = 0.f;
  } else if (idx < 139328){
    bar[idx - 135232] = 0u;   // flags[256*16]
  }
}

// ---------------- main persistent loop kernel ----------------
// R17 base (4824us, passing, bit-stable). Sync-only micro-opts this round:
//  (1) ctx gate: waves 0-3 poll the 64 B-flags directly (no LDS relay);
//  (2) B's t1 poll: 8-way wave-parallel (wave w polls flags w*32..w*32+31,
//      lanes 0-31), combined by __syncthreads();
//  (3) ctxT removed: L-blocks + epilogue read ctx from xT (R19-proven safe:
//      B's Phase-B(s+1) transitively waits on L's barrier-1(s+1)).
// FP sequence byte-identical to R17/R8.
__global__ __launch_bounds__(GTHR, 2) void k_loop(
    const float* __restrict__ w_ih, const float* __restrict__ w_hh,
    const int* __restrict__ batch_y, const float* __restrict__ tok,
    const float* __restrict__ keysum, const float* __restrict__ valsum,
    const float* __restrict__ cdnT, const float* __restrict__ cdn_b,
    float* __restrict__ xT, float* __restrict__ hT3,
    float* __restrict__ out, unsigned* __restrict__ flags){
  __shared__ float W_lds[1024][8];
  __shared__ float red[8][8][64];
  __shared__ float gates_lds[8][64];
  __shared__ float cc_lds[2][64];
  __shared__ float pb_h[512], pb_c[512];
  __shared__ float pb_lp[8][64];
  __shared__ float scr[8];
  __shared__ int done_h;

  const int tid = threadIdx.x;
  const int blk = blockIdx.x;
  const bool HASB = (blk < 64);
  const bool HASL = (blk >= 64 && blk < 128);

  if (tid == 0){ done_h = 0; }
  for (int idx = tid; idx < 8192; idx += GTHR){
    int k = idx >> 3, r = idx & 7;
    int g = r >> 1, c = r & 1;
    int row = g*512 + blk*2 + c;
    W_lds[k][r] = (k < 512) ? w_ih[row*1024 + 512 + k] : w_hh[row*512 + (k - 512)];
  }
  if (tid < 128) cc_lds[tid >> 6][tid & 63] = 0.0f;
  __syncthreads();

  const int w = tid >> 6, l = tid & 63, kg = l >> 4, bg = l & 15;
  const float SCALE = 22.627416997969522f;

#define ISS1(R, JJ) do{ const float* _p = xin + (((kbase + (JJ)*4) << 6) | (bg << 2)); \
  asm volatile("global_load_dwordx4 %0, %1, off sc0 sc1" : "=v"(R) : "v"(_p)); }while(0)
#define ISS8(P, J0) do{ ISS1(P##0,(J0)+0);ISS1(P##1,(J0)+1);ISS1(P##2,(J0)+2);ISS1(P##3,(J0)+3); \
  ISS1(P##4,(J0)+4);ISS1(P##5,(J0)+5);ISS1(P##6,(J0)+6);ISS1(P##7,(J0)+7); }while(0)
#define CMPX(R, JJ) do{ int _k = kbase + (JJ)*4; \
  f4v _wA = *(const f4v*)&W_lds[_k][0]; f4v _wB = *(const f4v*)&W_lds[_k][4]; \
  float _wv[8] = {_wA.x,_wA.y,_wA.z,_wA.w,_wB.x,_wB.y,_wB.z,_wB.w}; \
  float _xv[4] = {R.x,R.y,R.z,R.w}; \
  _Pragma("unroll") for (int _r = 0; _r < 8; ++_r){ \
    _Pragma("unroll") for (int _q = 0; _q < 4; ++_q) \
      acc[_r][_q] = fmaf(_wv[_r], _xv[_q], acc[_r][_q]); } }while(0)
#define CMP8(P, J0) do{ CMPX(P##0,(J0)+0);CMPX(P##1,(J0)+1);CMPX(P##2,(J0)+2);CMPX(P##3,(J0)+3); \
  CMPX(P##4,(J0)+4);CMPX(P##5,(J0)+5);CMPX(P##6,(J0)+6);CMPX(P##7,(J0)+7); }while(0)
#define WAITV(N) do{ asm volatile("s_waitcnt vmcnt(" #N ")" ::: "memory"); \
  __builtin_amdgcn_sched_barrier(0); }while(0)

  for (int s = 0; s < NSTEP; ++s){
    const float* xin  = xT + (size_t)(s & 1)*65536;
    float*       xout = xT + (size_t)((s + 1) & 1)*65536;
    const unsigned t1 = (unsigned)(2*s + 1), t2 = (unsigned)(2*s + 2);
    const unsigned tgt_h = (s == 0) ? 0u : (unsigned)(2*s - 1);
    const unsigned tgt_c = (s == 0) ? 0u : (unsigned)(2*s);

    // ---- per-wave input gating ----
    if (w >= 4){
      // h rows: wave-4 relay (pre-satisfied during prior Phase-B window)
      if (w == 4){
        poll256(flags, tgt_h);
        __hip_atomic_store(&done_h, s + 1, RLX, WGRP);
      } else {
        while (__hip_atomic_load(&done_h, RLX, WGRP) < s + 1) __builtin_amdgcn_s_sleep(1);
      }
    } else {
      // ctx rows: all 4 waves poll the 64 B-flags directly
      poll64(flags, tgt_c);
    }

    // tok prefetch (verbatim R8)
    const int rr = tid >> 6, rb = tid & 63;
    int yprev = (s == 0) ? 0 : batch_y[rb*200 + s];
    float tokval = tok[yprev*2048 + (rr >> 1)*512 + blk*2 + (rr & 1)];

    // ---- Phase A (verbatim R8) ----
    float acc[8][4];
    #pragma unroll
    for (int r = 0; r < 8; ++r)
      #pragma unroll
      for (int q = 0; q < 4; ++q) acc[r][q] = 0.f;

    const int kbase = w*128 + kg;
    {
      f4v A0,A1,A2,A3,A4,A5,A6,A7,B0,B1,B2,B3,B4,B5,B6,B7;
      ISS8(A, 0);
      ISS8(B, 8);
      WAITV(8); CMP8(A, 0);
      ISS8(A, 16);
      WAITV(8); CMP8(B, 8);
      ISS8(B, 24);
      WAITV(8); CMP8(A, 16);
      WAITV(0); CMP8(B, 24);
    }

    #pragma unroll
    for (int r = 0; r < 8; ++r)
      #pragma unroll
      for (int q = 0; q < 4; ++q){
        float v = acc[r][q];
        v += __shfl_xor(v, 16, 64);
        v += __shfl_xor(v, 32, 64);
        acc[r][q] = v;
      }
    if (l < 16){
      #pragma unroll
      for (int r = 0; r < 8; ++r)
        *(float4*)&red[w][r][bg*4] = make_float4(acc[r][0], acc[r][1], acc[r][2], acc[r][3]);
    }
    __syncthreads();
    {
      float g = 0.f;
      #pragma unroll
      for (int ww = 0; ww < 8; ++ww) g += red[ww][rr][rb];
      gates_lds[rr][rb] = g + tokval;
    }
    __syncthreads();
    if (tid < 128){
      int c = tid >> 6, b = tid & 63;
      float ig = gates_lds[0 + c][b];
      float fg = gates_lds[2 + c][b];
      float gg = gates_lds[4 + c][b];
      float og = gates_lds[6 + c][b];
      float cprev = cc_lds[c][b];
      float cnew = sigf(fg)*cprev + sigf(ig)*tanhf(gg);
      float hnew = sigf(og)*tanhf(cnew);
      cc_lds[c][b] = cnew;
      float oldh = __hip_atomic_exchange(&xout[(512 + blk*2 + c)*64 + b], hnew, RLX, AGENT);
      asm volatile("" :: "v"(oldh));
      float oldt = __hip_atomic_exchange(
          &hT3[(size_t)((s + 1) % 3)*32768 + b*512 + (blk*2 + c)], hnew, RLX, AGENT);
      asm volatile("" :: "v"(oldt));
    }

    // ---- barrier-1 arrival ----
    asm volatile("s_waitcnt vmcnt(0)" ::: "memory");
    __syncthreads();
    if (tid == 0){
      unsigned o = __hip_atomic_exchange(&flags[blk*16], HASB ? t1 : t2, RLX, AGENT);
      asm volatile("" :: "v"(o));
    }

    if (HASB){
      // 8-way wave-parallel t1 poll; __syncthreads is the combine
      if (l < 32){
        unsigned fidx = (unsigned)((w*32 + l)*16);
        while (__hip_atomic_load(&flags[fidx], RLX, AGENT) < t1){
          __builtin_amdgcn_s_sleep(1);
        }
      }
      __syncthreads();

      // ---- Phase B core (softmax + ctx scatter; FP verbatim R8) ----
      int b = blk;
      int jj = tid;
      float h;
      { const float* hp = hT3 + (size_t)((s + 1) % 3)*32768 + b*512 + jj;
        asm volatile("global_load_dword %0, %1, off sc0 sc1" : "=v"(h) : "v"(hp));
        asm volatile("s_waitcnt vmcnt(0)" ::: "memory"); }
      pb_h[jj] = h;
      float sc = (keysum[b*512 + jj] * h) / SCALE;
      float m = blk_red_max(sc, scr);
      float e = expf(sc - m);
      float S = blk_red_sum(e, scr);
      float cx = valsum[b*512 + jj] * (e / S);
      float oldc = __hip_atomic_exchange(&xout[jj*64 + b], cx, RLX, AGENT);
      asm volatile("" :: "v"(oldc));
      asm volatile("s_waitcnt vmcnt(0)" ::: "memory");
      __syncthreads();
      if (tid == 0){
        unsigned o = __hip_atomic_exchange(&flags[blk*16], t2, RLX, AGENT);
        asm volatile("" :: "v"(o));
      }
    }

    if (HASL && s >= 1){
      // ---- pipelined logits + sampling for sp = s-1 (off critical path) ----
      // ctx(s) from xT slot (s&1): stable until B's Phase-B(s+1), which
      // transitively waits on this block's barrier-1(s+1).
      int b = blk - 64;
      int sp = s - 1;
      float h, c;
      { const float* hp = hT3 + (size_t)(s % 3)*32768 + b*512 + tid;
        const float* cp = xT + (size_t)(s & 1)*65536 + tid*64 + b;
        asm volatile("global_load_dword %0, %1, off sc0 sc1" : "=v"(h) : "v"(hp));
        asm volatile("global_load_dword %0, %1, off sc0 sc1" : "=v"(c) : "v"(cp));
        asm volatile("s_waitcnt vmcnt(0)" ::: "memory"); }
      pb_h[tid] = h;
      pb_c[tid] = c;
      __syncthreads();
      int kq = tid >> 6, v = tid & 63;
      float part = 0.f;
      for (int k = kq*128; k < kq*128 + 128; ++k){
        float xh = (k < 512) ? pb_h[k] : pb_c[k - 512];
        part = fmaf(cdnT[k*64 + v], xh, part);
      }
      pb_lp[kq][v] = part;
      __syncthreads();
      if (tid < 64){
        int v2 = tid;
        float logit = cdn_b[v2];
        #pragma unroll
        for (int q = 0; q < 8; ++q) logit += pb_lp[q][v2];
        out[b*12800 + (sp+1)*64 + v2] = logit;
        float z = gumbel_tf((unsigned)((b*199 + sp)*64 + v2)) + logit;
        int idx = v2;
        #pragma unroll
        for (int mm = 1; mm < 64; mm <<= 1){
          float oz = __shfl_xor(z, mm, 64);
          int   oi = __shfl_xor(idx, mm, 64);
          if (oz > z || (oz == z && oi < idx)){ z = oz; idx = oi; }
        }
        if (v2 == 0) out[819200 + b*200 + (sp+1)] = (float)idx;
      }
    }
  }

  // ---- epilogue: logits/sampling for sp = 198 (L-blocks) ----
  if (HASL){
    int b = blk - 64;
    const int sp = NSTEP - 1;                      // 198
    if (tid == 0){
      while (__hip_atomic_load(&flags[b*16], RLX, AGENT) < (unsigned)(2*sp + 2))
        __builtin_amdgcn_s_sleep(1);
    }
    __syncthreads();
    float h, c;
    { const float* hp = hT3 + (size_t)((sp + 1) % 3)*32768 + b*512 + tid;
      const float* cp = xT + (size_t)((sp + 1) & 1)*65536 + tid*64 + b;
      asm volatile("global_load_dword %0, %1, off sc0 sc1" : "=v"(h) : "v"(hp));
      asm volatile("global_load_dword %0, %1, off sc0 sc1" : "=v"(c) : "v"(cp));
      asm volatile("s_waitcnt vmcnt(0)" ::: "memory"); }
    pb_h[tid] = h;
    pb_c[tid] = c;
    __syncthreads();
    int kq = tid >> 6, v = tid & 63;
    float part = 0.f;
    for (int k = kq*128; k < kq*128 + 128; ++k){
      float xh = (k < 512) ? pb_h[k] : pb_c[k - 512];
      part = fmaf(cdnT[k*64 + v], xh, part);
    }
    pb_lp[kq][v] = part;
    __syncthreads();
    if (tid < 64){
      int v2 = tid;
      float logit = cdn_b[v2];
      #pragma unroll
      for (int q = 0; q < 8; ++q) logit += pb_lp[q][v2];
      out[b*12800 + (sp+1)*64 + v2] = logit;
      float z = gumbel_tf((unsigned)((b*199 + sp)*64 + v2)) + logit;
      int idx = v2;
      #pragma unroll
      for (int mm = 1; mm < 64; mm <<= 1){
        float oz = __shfl_xor(z, mm, 64);
        int   oi = __shfl_xor(idx, mm, 64);
        if (oz > z || (oz == z && oi < idx)){ z = oz; idx = oi; }
      }
      if (v2 == 0) out[819200 + b*200 + (sp+1)] = (float)idx;
    }
  }
#undef ISS1
#undef ISS8
#undef CMPX
#undef CMP8
#undef WAITV
}

// ---------------- launcher ----------------
extern "C" void kernel_launch(void* const* d_in, const int* in_sizes, int n_in,
                              void* d_out, int out_size, void* d_ws, size_t ws_size,
                              hipStream_t stream){
  const float* seq     = (const float*)d_in[0];
  const float* key_w   = (const float*)d_in[1];
  const float* key_b   = (const float*)d_in[2];
  const float* value_w = (const float*)d_in[3];
  const float* value_b = (const float*)d_in[4];
  const float* char_e  = (const float*)d_in[5];
  const float* w_ih    = (const float*)d_in[6];
  const float* w_hh    = (const float*)d_in[7];
  const float* b_ih    = (const float*)d_in[8];
  const float* b_hh    = (const float*)d_in[9];
  const float* cdn_w   = (const float*)d_in[10];
  const float* cdn_b   = (const float*)d_in[11];
  const int*   lens    = (const int*)d_in[12];
  const int*   batch_y = (const int*)d_in[13];
  float* out = (float*)d_out;
  float* ws  = (float*)d_ws;

  // R8-proven 2.9 MB footprint. hT3 overlays the msum_part scratch (dead
  // after k_msum; k_loop writes each slot before any gated read).
  float* hT3       = ws;              // 3 x 32768  [b][row]
  float* msum_part = ws;              // 262144 (precompute only)
  float* msumT     = ws + 262144;
  float* keysum    = ws + 294912;
  float* valsum    = ws + 327680;
  float* tok       = ws + 360448;
  float* cdnT      = ws + 491520;
  float* ceT       = ws + 557056;
  float* xT        = ws + 589824;     // 2 x 65536
  unsigned* bar    = (unsigned*)(ws + 720896); // flags[256*16]

  k_msum_part<<<512, 256, 0, stream>>>(seq, lens, msum_part);
  k_msum     <<<64,  256, 0, stream>>>(msum_part, msumT);
  k_kv       <<<256, 256, 0, stream>>>(msumT, key_w, key_b, value_w, value_b, keysum, valsum);
  k_ceT      <<<128, 256, 0, stream>>>(char_e, ceT);
  k_tok      <<<512, 256, 0, stream>>>(ceT, w_ih, b_ih, b_hh, tok);
  k_init     <<<545, 256, 0, stream>>>(valsum, cdn_w, cdnT, xT, out, bar);

  k_loop<<<GBLK, GTHR, 0, stream>>>(w_ih, w_hh, batch_y, tok, keysum, valsum,
                                    cdnT, cdn_b, xT, hT3, out, bar);
  (void)in_sizes; (void)n_in; (void)out_size; (void)ws_size;
}

// Round 22
// 4796.847 us; speedup vs baseline: 3.4116x; 1.0276x over previous
//
#include <hip/hip_runtime.h>
#include <math.h>

#define NB 64
#define NH 512
#define NV 64
#define NT 200
#define NSTEP 199
#define GBLK 256
#define GTHR 512

#define RLX   __ATOMIC_RELAXED
#define AGENT __HIP_MEMORY_SCOPE_AGENT
#define WGRP  __HIP_MEMORY_SCOPE_WORKGROUP

typedef float f4v __attribute__((ext_vector_type(4)));

// ---------------- threefry / gumbel (verbatim R8) -------------------------
__device__ inline float gumbel_tf(unsigned f){
  const unsigned ksc[3] = {0u, 1u, 0x1BD11BDBu};
  unsigned x0 = 0u + ksc[0];
  unsigned x1 = f  + ksc[1];
  const int R0[4] = {13,15,26,6};
  const int R1[4] = {17,29,16,24};
  #pragma unroll
  for (int i = 0; i < 5; ++i){
    #pragma unroll
    for (int r = 0; r < 4; ++r){
      int rot = (i & 1) ? R1[r] : R0[r];
      x0 += x1;
      x1 = (x1 << rot) | (x1 >> (32 - rot));
      x1 ^= x0;
    }
    x0 += ksc[(i+1)%3];
    x1 += ksc[(i+2)%3] + (unsigned)(i+1);
  }
  unsigned bits = x0 ^ x1;
  float u = __uint_as_float((bits >> 9) | 0x3F800000u) - 1.0f;
  u = fmaxf(u, 1.17549435e-38f);
  return -logf(-logf(u));
}

__device__ inline float sigf(float x){ return 1.0f/(1.0f + expf(-x)); }

// ---------------- flag polls ----------------
// all 256 flags (one wave: 64 lanes x 4)
__device__ inline void poll256(unsigned* flags, unsigned tgt){
  const int l = threadIdx.x & 63;
  #pragma unroll
  for (int j = 0; j < 4; ++j){
    while (__hip_atomic_load(&flags[(l*4 + j)*16], RLX, AGENT) < tgt){
      __builtin_amdgcn_s_sleep(1);
    }
  }
}
// B-block flags only (0..63), one lane each
__device__ inline void poll64(unsigned* flags, unsigned tgt){
  const int l = threadIdx.x & 63;
  while (__hip_atomic_load(&flags[l*16], RLX, AGENT) < tgt){
    __builtin_amdgcn_s_sleep(1);
  }
}

// ---------------- block reductions (verbatim R8) ----------------
__device__ inline float blk_red_max(float v, float* scr){
  #pragma unroll
  for (int m = 1; m < 64; m <<= 1) v = fmaxf(v, __shfl_xor(v, m, 64));
  if ((threadIdx.x & 63) == 0) scr[threadIdx.x >> 6] = v;
  __syncthreads();
  float r = scr[0];
  #pragma unroll
  for (int i = 1; i < 8; ++i) r = fmaxf(r, scr[i]);
  __syncthreads();
  return r;
}
__device__ inline float blk_red_sum(float v, float* scr){
  #pragma unroll
  for (int m = 1; m < 64; m <<= 1) v += __shfl_xor(v, m, 64);
  if ((threadIdx.x & 63) == 0) scr[threadIdx.x >> 6] = v;
  __syncthreads();
  float r = 0.f;
  #pragma unroll
  for (int i = 0; i < 8; ++i) r += scr[i];
  __syncthreads();
  return r;
}

// ---------------- precompute kernels (verbatim R8) -----------
__global__ void k_msum_part(const float* __restrict__ emb, const int* __restrict__ lens,
                            float* __restrict__ part){
  int blk = blockIdx.x, b = blk >> 3, lc = blk & 7;
  int len = lens[b];
  int l0 = lc*64, l1 = len < l0+64 ? len : l0+64;
  for (int h = threadIdx.x; h < 512; h += 256){
    float a = 0.f;
    for (int l = l0; l < l1; ++l) a += emb[(b*512 + l)*512 + h];
    part[blk*512 + h] = a;
  }
}
__global__ void k_msum(const float* __restrict__ part, float* __restrict__ msumT){
  int b = blockIdx.x;
  for (int h = threadIdx.x; h < 512; h += 256){
    float a = 0.f;
    #pragma unroll
    for (int lc = 0; lc < 8; ++lc) a += part[(b*8+lc)*512 + h];
    msumT[h*64 + b] = a;
  }
}
__global__ void k_kv(const float* __restrict__ msumT,
                     const float* __restrict__ kw, const float* __restrict__ kb,
                     const float* __restrict__ vw, const float* __restrict__ vb,
                     float* __restrict__ keysum, float* __restrict__ valsum){
  int which = blockIdx.x >> 7;
  int i = ((blockIdx.x & 127) << 2) + (threadIdx.x >> 6);
  int b = threadIdx.x & 63;
  const float* W = which ? vw : kw;
  float a = 0.f;
  for (int h = 0; h < 512; ++h) a = fmaf(msumT[h*64+b], W[i*512+h], a);
  float bias = which ? vb[i] : kb[i];
  float* out = which ? valsum : keysum;
  out[b*512 + i] = a + 512.0f*bias;
}
__global__ void k_ceT(const float* __restrict__ ce, float* __restrict__ ceT){
  int idx = blockIdx.x*256 + threadIdx.x;
  if (idx < 32768){ int v = idx >> 9, e = idx & 511; ceT[e*64 + v] = ce[v*512 + e]; }
}
__global__ void k_tok(const float* __restrict__ ceT, const float* __restrict__ w_ih,
                      const float* __restrict__ b_ih, const float* __restrict__ b_hh,
                      float* __restrict__ tok){
  int idx = blockIdx.x*256 + threadIdx.x;
  int v = idx & 63, row = idx >> 6;
  float a = 0.f;
  for (int e = 0; e < 512; ++e) a = fmaf(ceT[e*64+v], w_ih[row*1024 + e], a);
  tok[v*2048 + row] = a + b_ih[row] + b_hh[row];
}
__global__ void k_init(const float* __restrict__ valsum, const float* __restrict__ cdn_w,
                       float* __restrict__ cdnT, float* __restrict__ xT,
                       float* __restrict__ out, unsigned* __restrict__ bar){
  int idx = blockIdx.x*256 + threadIdx.x;
  if (idx < 65536){
    int v = idx >> 10, k = idx & 1023;
    cdnT[k*64 + v] = cdn_w[idx];
  } else if (idx < 98304){
    int r = idx - 65536; int j = r >> 6, b = r & 63;
    xT[j*64 + b] = valsum[b*512 + j] * (1.0f/512.0f);
  } else if (idx < 131072){
    xT[idx - 65536] = 0.f;
  } else if (idx < 135168){
    int r = idx - 131072; int b = r >> 6, v = r & 63;
    out[b*12800 + v] = 0.f;
  } else if (idx < 135232){
    int b = idx - 135168;
    out[819200 + b*200] = 0.f;
  } else if (idx < 139328){
    bar[idx - 135232] = 0u;   // flags[256*16]
  }
}

// ---------------- main persistent loop kernel ----------------
// R17: R8 FP sequence byte-preserved; role-split (B: softmax+ctx; L: pipelined
// logits+sampling for step s-1); coalesced h gathers via transposed hT3.
__global__ __launch_bounds__(GTHR, 2) void k_loop(
    const float* __restrict__ w_ih, const float* __restrict__ w_hh,
    const int* __restrict__ batch_y, const float* __restrict__ tok,
    const float* __restrict__ keysum, const float* __restrict__ valsum,
    const float* __restrict__ cdnT, const float* __restrict__ cdn_b,
    float* __restrict__ xT, float* __restrict__ hT3, float* __restrict__ ctxT,
    float* __restrict__ out, unsigned* __restrict__ flags){
  __shared__ float W_lds[1024][8];
  __shared__ float red[8][8][64];
  __shared__ float gates_lds[8][64];
  __shared__ float cc_lds[2][64];
  __shared__ float pb_h[512], pb_c[512];
  __shared__ float pb_lp[8][64];
  __shared__ float scr[8];
  __shared__ int done_h, done_c, done_pb;

  const int tid = threadIdx.x;
  const int blk = blockIdx.x;
  const bool HASB = (blk < 64);
  const bool HASL = (blk >= 64 && blk < 128);

  if (tid == 0){ done_h = 0; done_c = 0; done_pb = 0; }
  for (int idx = tid; idx < 8192; idx += GTHR){
    int k = idx >> 3, r = idx & 7;
    int g = r >> 1, c = r & 1;
    int row = g*512 + blk*2 + c;
    W_lds[k][r] = (k < 512) ? w_ih[row*1024 + 512 + k] : w_hh[row*512 + (k - 512)];
  }
  if (tid < 128) cc_lds[tid >> 6][tid & 63] = 0.0f;
  __syncthreads();

  const int w = tid >> 6, l = tid & 63, kg = l >> 4, bg = l & 15;
  const float SCALE = 22.627416997969522f;

#define ISS1(R, JJ) do{ const float* _p = xin + (((kbase + (JJ)*4) << 6) | (bg << 2)); \
  asm volatile("global_load_dwordx4 %0, %1, off sc0 sc1" : "=v"(R) : "v"(_p)); }while(0)
#define ISS8(P, J0) do{ ISS1(P##0,(J0)+0);ISS1(P##1,(J0)+1);ISS1(P##2,(J0)+2);ISS1(P##3,(J0)+3); \
  ISS1(P##4,(J0)+4);ISS1(P##5,(J0)+5);ISS1(P##6,(J0)+6);ISS1(P##7,(J0)+7); }while(0)
#define CMP1(R, JJ) do{ int _k = kbase + (JJ)*4; \
  f4v _wA = *(const f4v*)&W_lds[_k][0]; f4v _wB = *(const f4v*)&W_lds[_k][4]; \
  float _wv[8] = {_wA.x,_wA.y,_wA.z,_wA.w,_wB.x,_wB.y,_wB.z,_wB.w}; \
  float _xv[4] = {R.x,R.y,R.z,R.w}; \
  _Pragma("unroll") for (int _r = 0; _r < 8; ++_r){ \
    _Pragma("unroll") for (int _q = 0; _q < 4; ++_q) \
      acc[_r][_q] = fmaf(_wv[_r], _xv[_q], acc[_r][_q]); } }while(0)
#define CMP8(P, J0) do{ CMP1(P##0,(J0)+0);CMP1(P##1,(J0)+1);CMP1(P##2,(J0)+2);CMP1(P##3,(J0)+3); \
  CMP1(P##4,(J0)+4);CMP1(P##5,(J0)+5);CMP1(P##6,(J0)+6);CMP1(P##7,(J0)+7); }while(0)
#define WAITV(N) do{ asm volatile("s_waitcnt vmcnt(" #N ")" ::: "memory"); \
  __builtin_amdgcn_sched_barrier(0); }while(0)

  for (int s = 0; s < NSTEP; ++s){
    const float* xin  = xT + (size_t)(s & 1)*65536;
    float*       xout = xT + (size_t)((s + 1) & 1)*65536;
    const unsigned t1 = (unsigned)(2*s + 1), t2 = (unsigned)(2*s + 2);
    const unsigned tgt_h = (s == 0) ? 0u : (unsigned)(2*s - 1);
    const unsigned tgt_c = (s == 0) ? 0u : (unsigned)(2*s);

    // ---- per-wave input gating ----
    if (w >= 4){
      if (w == 4){
        poll256(flags, tgt_h);
        __hip_atomic_store(&done_h, s + 1, RLX, WGRP);
      } else {
        while (__hip_atomic_load(&done_h, RLX, WGRP) < s + 1) __builtin_amdgcn_s_sleep(1);
      }
    } else {
      if (w == 0){
        poll64(flags, tgt_c);
        __hip_atomic_store(&done_c, s + 1, RLX, WGRP);
      } else {
        while (__hip_atomic_load(&done_c, RLX, WGRP) < s + 1) __builtin_amdgcn_s_sleep(1);
      }
    }

    // tok prefetch (verbatim R8)
    const int rr = tid >> 6, rb = tid & 63;
    int yprev = (s == 0) ? 0 : batch_y[rb*200 + s];
    float tokval = tok[yprev*2048 + (rr >> 1)*512 + blk*2 + (rr & 1)];

    // ---- Phase A (verbatim R8) ----
    float acc[8][4];
    #pragma unroll
    for (int r = 0; r < 8; ++r)
      #pragma unroll
      for (int q = 0; q < 4; ++q) acc[r][q] = 0.f;

    const int kbase = w*128 + kg;
    {
      f4v A0,A1,A2,A3,A4,A5,A6,A7,B0,B1,B2,B3,B4,B5,B6,B7;
      ISS8(A, 0);
      ISS8(B, 8);
      WAITV(8); CMP8(A, 0);
      ISS8(A, 16);
      WAITV(8); CMP8(B, 8);
      ISS8(B, 24);
      WAITV(8); CMP8(A, 16);
      WAITV(0); CMP8(B, 24);
    }

    #pragma unroll
    for (int r = 0; r < 8; ++r)
      #pragma unroll
      for (int q = 0; q < 4; ++q){
        float v = acc[r][q];
        v += __shfl_xor(v, 16, 64);
        v += __shfl_xor(v, 32, 64);
        acc[r][q] = v;
      }
    if (l < 16){
      #pragma unroll
      for (int r = 0; r < 8; ++r)
        *(float4*)&red[w][r][bg*4] = make_float4(acc[r][0], acc[r][1], acc[r][2], acc[r][3]);
    }
    __syncthreads();
    {
      float g = 0.f;
      #pragma unroll
      for (int ww = 0; ww < 8; ++ww) g += red[ww][rr][rb];
      gates_lds[rr][rb] = g + tokval;
    }
    __syncthreads();
    if (tid < 128){
      int c = tid >> 6, b = tid & 63;
      float ig = gates_lds[0 + c][b];
      float fg = gates_lds[2 + c][b];
      float gg = gates_lds[4 + c][b];
      float og = gates_lds[6 + c][b];
      float cprev = cc_lds[c][b];
      float cnew = sigf(fg)*cprev + sigf(ig)*tanhf(gg);
      float hnew = sigf(og)*tanhf(cnew);
      cc_lds[c][b] = cnew;
      float oldh = __hip_atomic_exchange(&xout[(512 + blk*2 + c)*64 + b], hnew, RLX, AGENT);
      asm volatile("" :: "v"(oldh));
      // transposed copy for coalesced gathers (same bits)
      float oldt = __hip_atomic_exchange(
          &hT3[(size_t)((s + 1) % 3)*32768 + b*512 + (blk*2 + c)], hnew, RLX, AGENT);
      asm volatile("" :: "v"(oldt));
    }

    // ---- barrier-1 arrival ----
    asm volatile("s_waitcnt vmcnt(0)" ::: "memory");
    __syncthreads();
    if (tid == 0){
      unsigned o = __hip_atomic_exchange(&flags[blk*16], HASB ? t1 : t2, RLX, AGENT);
      asm volatile("" :: "v"(o));
    }

    if (HASB){
      if (w == 4){
        poll256(flags, t1);
        __hip_atomic_store(&done_pb, s + 1, RLX, WGRP);
      } else {
        while (__hip_atomic_load(&done_pb, RLX, WGRP) < s + 1) __builtin_amdgcn_s_sleep(1);
      }

      // ---- Phase B core (softmax + ctx only; FP verbatim R8) ----
      int b = blk;
      int jj = tid;
      float h;
      { const float* hp = hT3 + (size_t)((s + 1) % 3)*32768 + b*512 + jj;
        asm volatile("global_load_dword %0, %1, off sc0 sc1" : "=v"(h) : "v"(hp));
        asm volatile("s_waitcnt vmcnt(0)" ::: "memory"); }
      pb_h[jj] = h;
      float sc = (keysum[b*512 + jj] * h) / SCALE;
      float m = blk_red_max(sc, scr);
      float e = expf(sc - m);
      float S = blk_red_sum(e, scr);
      float cx = valsum[b*512 + jj] * (e / S);
      float oldc = __hip_atomic_exchange(&xout[jj*64 + b], cx, RLX, AGENT);
      asm volatile("" :: "v"(oldc));
      float oldt = __hip_atomic_exchange(&ctxT[(size_t)(s & 1)*32768 + b*512 + jj], cx, RLX, AGENT);
      asm volatile("" :: "v"(oldt));
      asm volatile("s_waitcnt vmcnt(0)" ::: "memory");
      __syncthreads();
      if (tid == 0){
        unsigned o = __hip_atomic_exchange(&flags[blk*16], t2, RLX, AGENT);
        asm volatile("" :: "v"(o));
      }
    }

    if (HASL && s >= 1){
      // ---- pipelined logits + sampling for step sp = s-1 (off critical path).
      int b = blk - 64;
      int sp = s - 1;
      float h, c;
      { const float* hp = hT3 + (size_t)(s % 3)*32768 + b*512 + tid;
        const float* cp = ctxT + (size_t)(sp & 1)*32768 + b*512 + tid;
        asm volatile("global_load_dword %0, %1, off sc0 sc1" : "=v"(h) : "v"(hp));
        asm volatile("global_load_dword %0, %1, off sc0 sc1" : "=v"(c) : "v"(cp));
        asm volatile("s_waitcnt vmcnt(0)" ::: "memory"); }
      pb_h[tid] = h;
      pb_c[tid] = c;
      __syncthreads();
      int kq = tid >> 6, v = tid & 63;
      float part = 0.f;
      for (int k = kq*128; k < kq*128 + 128; ++k){
        float xh = (k < 512) ? pb_h[k] : pb_c[k - 512];
        part = fmaf(cdnT[k*64 + v], xh, part);
      }
      pb_lp[kq][v] = part;
      __syncthreads();
      if (tid < 64){
        int v2 = tid;
        float logit = cdn_b[v2];
        #pragma unroll
        for (int q = 0; q < 8; ++q) logit += pb_lp[q][v2];
        out[b*12800 + (sp+1)*64 + v2] = logit;
        float z = gumbel_tf((unsigned)((b*199 + sp)*64 + v2)) + logit;
        int idx = v2;
        #pragma unroll
        for (int mm = 1; mm < 64; mm <<= 1){
          float oz = __shfl_xor(z, mm, 64);
          int   oi = __shfl_xor(idx, mm, 64);
          if (oz > z || (oz == z && oi < idx)){ z = oz; idx = oi; }
        }
        if (v2 == 0) out[819200 + b*200 + (sp+1)] = (float)idx;
      }
    }
  }

  // ---- epilogue: logits/sampling for sp = NSTEP-1 = 198 (L-blocks) ----
  if (HASL){
    int b = blk - 64;
    const int sp = NSTEP - 1;                      // 198
    if (tid == 0){
      while (__hip_atomic_load(&flags[b*16], RLX, AGENT) < (unsigned)(2*sp + 2))
        __builtin_amdgcn_s_sleep(1);
    }
    __syncthreads();
    float h, c;
    { const float* hp = hT3 + (size_t)((sp + 1) % 3)*32768 + b*512 + tid;
      const float* cp = ctxT + (size_t)(sp & 1)*32768 + b*512 + tid;
      asm volatile("global_load_dword %0, %1, off sc0 sc1" : "=v"(h) : "v"(hp));
      asm volatile("global_load_dword %0, %1, off sc0 sc1" : "=v"(c) : "v"(cp));
      asm volatile("s_waitcnt vmcnt(0)" ::: "memory"); }
    pb_h[tid] = h;
    pb_c[tid] = c;
    __syncthreads();
    int kq = tid >> 6, v = tid & 63;
    float part = 0.f;
    for (int k = kq*128; k < kq*128 + 128; ++k){
      float xh = (k < 512) ? pb_h[k] : pb_c[k - 512];
      part = fmaf(cdnT[k*64 + v], xh, part);
    }
    pb_lp[kq][v] = part;
    __syncthreads();
    if (tid < 64){
      int v2 = tid;
      float logit = cdn_b[v2];
      #pragma unroll
      for (int q = 0; q < 8; ++q) logit += pb_lp[q][v2];
      out[b*12800 + (sp+1)*64 + v2] = logit;
      float z = gumbel_tf((unsigned)((b*199 + sp)*64 + v2)) + logit;
      int idx = v2;
      #pragma unroll
      for (int mm = 1; mm < 64; mm <<= 1){
        float oz = __shfl_xor(z, mm, 64);
        int   oi = __shfl_xor(idx, mm, 64);
        if (oz > z || (oz == z && oi < idx)){ z = oz; idx = oi; }
      }
      if (v2 == 0) out[819200 + b*200 + (sp+1)] = (float)idx;
    }
  }
#undef ISS1
#undef ISS8
#undef CMP1
#undef CMP8
#undef WAITV
}

// ---------------- launcher ----------------
extern "C" void kernel_launch(void* const* d_in, const int* in_sizes, int n_in,
                              void* d_out, int out_size, void* d_ws, size_t ws_size,
                              hipStream_t stream){
  const float* seq     = (const float*)d_in[0];
  const float* key_w   = (const float*)d_in[1];
  const float* key_b   = (const float*)d_in[2];
  const float* value_w = (const float*)d_in[3];
  const float* value_b = (const float*)d_in[4];
  const float* char_e  = (const float*)d_in[5];
  const float* w_ih    = (const float*)d_in[6];
  const float* w_hh    = (const float*)d_in[7];
  const float* b_ih    = (const float*)d_in[8];
  const float* b_hh    = (const float*)d_in[9];
  const float* cdn_w   = (const float*)d_in[10];
  const float* cdn_b   = (const float*)d_in[11];
  const int*   lens    = (const int*)d_in[12];
  const int*   batch_y = (const int*)d_in[13];
  float* out = (float*)d_out;
  float* ws  = (float*)d_ws;

  // R8-proven footprint. hT3/ctxT overlay the msum_part scratch (dead after
  // k_msum; k_loop writes each slot before any gated read).
  float* hT3       = ws;              // 3 x 32768  [b][row] transposed h
  float* ctxT      = ws + 98304;      // 2 x 32768  [b][row] transposed ctx
  float* msum_part = ws;              // 262144 (precompute only)
  float* msumT     = ws + 262144;     // 32768
  float* keysum    = ws + 294912;     // 32768
  float* valsum    = ws + 327680;     // 32768
  float* tok       = ws + 360448;     // 131072
  float* cdnT      = ws + 491520;     // 65536
  float* ceT       = ws + 557056;     // 32768
  float* xT        = ws + 589824;     // 2 x 65536 ping-pong
  unsigned* bar    = (unsigned*)(ws + 720896); // flags[256*16]

  k_msum_part<<<512, 256, 0, stream>>>(seq, lens, msum_part);
  k_msum     <<<64,  256, 0, stream>>>(msum_part, msumT);
  k_kv       <<<256, 256, 0, stream>>>(msumT, key_w, key_b, value_w, value_b, keysum, valsum);
  k_ceT      <<<128, 256, 0, stream>>>(char_e, ceT);
  k_tok      <<<512, 256, 0, stream>>>(ceT, w_ih, b_ih, b_hh, tok);
  k_init     <<<545, 256, 0, stream>>>(valsum, cdn_w, cdnT, xT, out, bar);

  k_loop<<<GBLK, GTHR, 0, stream>>>(w_ih, w_hh, batch_y, tok, keysum, valsum,
                                    cdnT, cdn_b, xT, hT3, ctxT, out, bar);
  (void)in_sizes; (void)n_in; (void)out_size; (void)ws_size;
}